// Round 5
// baseline (369.240 us; speedup 1.0000x reference)
//
#include <hip/hip_runtime.h>
#include <hip/hip_fp16.h>

#define F_IN 128
#define HID 128
#define HID4 32
#define NPB 64           // nodes per CSR bucket
#define SRC_BITS 17      // n_nodes = 50000 < 2^17

static inline size_t alignup(size_t x) { return (x + 255) & ~(size_t)255; }

union H4 { uint2 u; __half2 h[2]; };      // 4 halfs = 8 B
union F4H8 { float4 f; __half2 h[4]; };   // 8 halfs = 16 B

// ---------------- degree histogram ----------------

__global__ void deg_count_k(const int* __restrict__ dst, int* __restrict__ deg, int ne) {
    int e = blockIdx.x * blockDim.x + threadIdx.x;
    if (e < ne) atomicAdd(&deg[dst[e]], 1);
}

// ---------------- exclusive scan of deg -> rowoff ----------------

__global__ void scan_block_k(const int* __restrict__ deg, int* __restrict__ rowoff,
                             int* __restrict__ partials, int n) {
    __shared__ int tmp[256];
    int i = blockIdx.x * 256 + threadIdx.x;
    int v = (i < n) ? deg[i] : 0;
    tmp[threadIdx.x] = v;
    __syncthreads();
    for (int off = 1; off < 256; off <<= 1) {
        int t = (threadIdx.x >= off) ? tmp[threadIdx.x - off] : 0;
        __syncthreads();
        tmp[threadIdx.x] += t;
        __syncthreads();
    }
    if (i < n) rowoff[i] = tmp[threadIdx.x] - v;
    if (threadIdx.x == 255) partials[blockIdx.x] = tmp[255];
}

__global__ void scan_partials_k(int* __restrict__ partials, int nb) {
    __shared__ int tmp[256];
    int v = (threadIdx.x < nb) ? partials[threadIdx.x] : 0;
    tmp[threadIdx.x] = v;
    __syncthreads();
    for (int off = 1; off < 256; off <<= 1) {
        int t = (threadIdx.x >= off) ? tmp[threadIdx.x - off] : 0;
        __syncthreads();
        tmp[threadIdx.x] += t;
        __syncthreads();
    }
    if (threadIdx.x < nb) partials[threadIdx.x] = tmp[threadIdx.x] - v;
}

// finalize rowoff, compute dis, seed per-bucket cursors
__global__ void add_offsets_k(const int* __restrict__ deg, float* __restrict__ dis,
                              int* __restrict__ rowoff, int* __restrict__ bucket_cur,
                              const int* __restrict__ partials, int n) {
    int i = blockIdx.x * 256 + threadIdx.x;
    if (i < n) {
        int r = rowoff[i] + partials[i >> 8];
        rowoff[i] = r;
        if ((i & (NPB - 1)) == 0) bucket_cur[i / NPB] = r;
        dis[i] = rsqrtf((float)(deg[i] + 1));
    }
}

// ---------------- CSR build pass A: bin edges by dst-bucket ----------------
// tmp entry: (d % NPB) << SRC_BITS | src

__global__ void binA_k(const int* __restrict__ src, const int* __restrict__ dst,
                       int* __restrict__ bucket_cur, unsigned* __restrict__ tmp, int ne) {
    int e = blockIdx.x * blockDim.x + threadIdx.x;
    if (e >= ne) return;
    int s = src[e];
    int d = dst[e];
    int pos = atomicAdd(&bucket_cur[d / NPB], 1);
    tmp[pos] = ((unsigned)(d & (NPB - 1)) << SRC_BITS) | (unsigned)s;
}

// ---------------- CSR build pass B: order within bucket ----------------

__global__ __launch_bounds__(256) void binB_k(const unsigned* __restrict__ tmp,
                                              const int* __restrict__ rowoff,
                                              int* __restrict__ csr, int n_nodes, int ne) {
    __shared__ int cnt[NPB];
    __shared__ int roff_s[NPB];
    const int t = threadIdx.x;
    const int base = blockIdx.x * NPB;
    if (t < NPB) {
        cnt[t] = 0;
        int idx = base + t;
        roff_s[t] = (idx < n_nodes) ? rowoff[idx] : ne;
    }
    __syncthreads();
    int beg = roff_s[0];
    int end = (base + NPB < n_nodes) ? rowoff[base + NPB] : ne;
    for (int j = beg + t; j < end; j += 256) {
        unsigned e = tmp[j];
        int ld = e >> SRC_BITS;
        int s  = e & ((1u << SRC_BITS) - 1);
        int pos = roff_s[ld] + atomicAdd(&cnt[ld], 1);
        csr[pos] = s;
    }
}

// ---------------- GEMM1: g[n][128] (fp16) = dis[n] * (in[n][128] @ W[128][128]) ----------------

__global__ __launch_bounds__(256) void gemm1_k(const float* __restrict__ in,
                                               const float* __restrict__ W,
                                               const float* __restrict__ dis,
                                               __half* __restrict__ hout, int n_rows) {
    __shared__ float xs[64][132];
    __shared__ float wt[32][128];
    const int t = threadIdx.x;
    const int row0 = blockIdx.x * 64;

    #pragma unroll
    for (int i = 0; i < 8; ++i) {
        int q = t + i * 256;
        int row = q >> 5, c4 = (q & 31) * 4;
        float4 v = make_float4(0.f, 0.f, 0.f, 0.f);
        if (row0 + row < n_rows) v = *(const float4*)(in + (size_t)(row0 + row) * 128 + c4);
        *(float4*)&xs[row][c4] = v;
    }

    const int c4a = (t & 15) * 4;
    const int r4 = (t >> 4) * 4;

    float acc[4][8];
    #pragma unroll
    for (int i = 0; i < 4; ++i)
        #pragma unroll
        for (int j = 0; j < 8; ++j) acc[i][j] = 0.f;

    for (int kt = 0; kt < 4; ++kt) {
        __syncthreads();
        #pragma unroll
        for (int i = 0; i < 4; ++i) {
            int q = t + i * 256;
            int kk = q >> 5, c4 = (q & 31) * 4;
            *(float4*)&wt[kk][c4] = *(const float4*)(W + (size_t)(kt * 32 + kk) * 128 + c4);
        }
        __syncthreads();
        #pragma unroll 4
        for (int k = 0; k < 32; ++k) {
            float xv[4];
            #pragma unroll
            for (int i = 0; i < 4; ++i) xv[i] = xs[r4 + i][kt * 32 + k];
            float4 w0 = *(float4*)&wt[k][c4a];
            float4 w1 = *(float4*)&wt[k][64 + c4a];
            #pragma unroll
            for (int i = 0; i < 4; ++i) {
                acc[i][0] += xv[i] * w0.x; acc[i][1] += xv[i] * w0.y;
                acc[i][2] += xv[i] * w0.z; acc[i][3] += xv[i] * w0.w;
                acc[i][4] += xv[i] * w1.x; acc[i][5] += xv[i] * w1.y;
                acc[i][6] += xv[i] * w1.z; acc[i][7] += xv[i] * w1.w;
            }
        }
    }

    #pragma unroll
    for (int i = 0; i < 4; ++i) {
        int row = row0 + r4 + i;
        if (row < n_rows) {
            float sc = dis[row];
            __half* p = hout + (size_t)row * 128;
            H4 a, b;
            a.h[0] = __floats2half2_rn(sc * acc[i][0], sc * acc[i][1]);
            a.h[1] = __floats2half2_rn(sc * acc[i][2], sc * acc[i][3]);
            b.h[0] = __floats2half2_rn(sc * acc[i][4], sc * acc[i][5]);
            b.h[1] = __floats2half2_rn(sc * acc[i][6], sc * acc[i][7]);
            *(uint2*)(p + c4a) = a.u;
            *(uint2*)(p + 64 + c4a) = b.u;
        }
    }
}

// ---------------- GEMM2: g[n][32] = dis[n] * (relu(in[n][128]) @ W[128][32]) ----------------

__global__ __launch_bounds__(256) void gemm2_k(const float* __restrict__ in,
                                               const float* __restrict__ W,
                                               const float* __restrict__ dis,
                                               float* __restrict__ out, int n_rows) {
    __shared__ float xs[64][132];
    __shared__ float wt[128][32];
    const int t = threadIdx.x;
    const int row0 = blockIdx.x * 64;

    #pragma unroll
    for (int i = 0; i < 8; ++i) {
        int q = t + i * 256;
        int row = q >> 5, c4 = (q & 31) * 4;
        float4 v = make_float4(0.f, 0.f, 0.f, 0.f);
        if (row0 + row < n_rows) {
            v = *(const float4*)(in + (size_t)(row0 + row) * 128 + c4);
            v.x = fmaxf(v.x, 0.f); v.y = fmaxf(v.y, 0.f);
            v.z = fmaxf(v.z, 0.f); v.w = fmaxf(v.w, 0.f);
        }
        *(float4*)&xs[row][c4] = v;
    }
    #pragma unroll
    for (int i = 0; i < 4; ++i) {
        int q = t + i * 256;
        int kk = q >> 3, c4 = (q & 7) * 4;
        *(float4*)&wt[kk][c4] = *(const float4*)(W + (size_t)kk * 32 + c4);
    }
    __syncthreads();

    const int c4 = (t & 7) * 4;
    const int r2 = (t >> 3) * 2;

    float acc[2][4];
    #pragma unroll
    for (int i = 0; i < 2; ++i)
        #pragma unroll
        for (int j = 0; j < 4; ++j) acc[i][j] = 0.f;

    #pragma unroll 4
    for (int k = 0; k < 128; ++k) {
        float x0 = xs[r2][k], x1 = xs[r2 + 1][k];
        float4 w = *(float4*)&wt[k][c4];
        acc[0][0] += x0 * w.x; acc[0][1] += x0 * w.y; acc[0][2] += x0 * w.z; acc[0][3] += x0 * w.w;
        acc[1][0] += x1 * w.x; acc[1][1] += x1 * w.y; acc[1][2] += x1 * w.z; acc[1][3] += x1 * w.w;
    }

    #pragma unroll
    for (int i = 0; i < 2; ++i) {
        int row = row0 + r2 + i;
        if (row < n_rows) {
            float sc = dis[row];
            *(float4*)(out + (size_t)row * 32 + c4) =
                make_float4(sc * acc[i][0], sc * acc[i][1], sc * acc[i][2], sc * acc[i][3]);
        }
    }
}

// ---------------- GEMM3: g[n][32] = dis[n] * (relu(in[n][32]) @ W[32][32]) ----------------

__global__ __launch_bounds__(256) void gemm3_k(const float* __restrict__ in,
                                               const float* __restrict__ W,
                                               const float* __restrict__ dis,
                                               float* __restrict__ out, int n_rows) {
    __shared__ float xs[64][36];
    __shared__ float wt[32][32];
    const int t = threadIdx.x;
    const int row0 = blockIdx.x * 64;

    #pragma unroll
    for (int i = 0; i < 2; ++i) {
        int q = t + i * 256;
        int row = q >> 3, c4 = (q & 7) * 4;
        float4 v = make_float4(0.f, 0.f, 0.f, 0.f);
        if (row0 + row < n_rows) {
            v = *(const float4*)(in + (size_t)(row0 + row) * 32 + c4);
            v.x = fmaxf(v.x, 0.f); v.y = fmaxf(v.y, 0.f);
            v.z = fmaxf(v.z, 0.f); v.w = fmaxf(v.w, 0.f);
        }
        *(float4*)&xs[row][c4] = v;
    }
    {
        int kk = t >> 3, c4 = (t & 7) * 4;
        *(float4*)&wt[kk][c4] = *(const float4*)(W + (size_t)kk * 32 + c4);
    }
    __syncthreads();

    const int c4 = (t & 7) * 4;
    const int r2 = (t >> 3) * 2;

    float acc[2][4];
    #pragma unroll
    for (int i = 0; i < 2; ++i)
        #pragma unroll
        for (int j = 0; j < 4; ++j) acc[i][j] = 0.f;

    #pragma unroll
    for (int k = 0; k < 32; ++k) {
        float x0 = xs[r2][k], x1 = xs[r2 + 1][k];
        float4 w = *(float4*)&wt[k][c4];
        acc[0][0] += x0 * w.x; acc[0][1] += x0 * w.y; acc[0][2] += x0 * w.z; acc[0][3] += x0 * w.w;
        acc[1][0] += x1 * w.x; acc[1][1] += x1 * w.y; acc[1][2] += x1 * w.z; acc[1][3] += x1 * w.w;
    }

    #pragma unroll
    for (int i = 0; i < 2; ++i) {
        int row = row0 + r2 + i;
        if (row < n_rows) {
            float sc = dis[row];
            *(float4*)(out + (size_t)row * 32 + c4) =
                make_float4(sc * acc[i][0], sc * acc[i][1], sc * acc[i][2], sc * acc[i][3]);
        }
    }
}

// ---------------- pull1 (fp16 g, 128-wide): 16 lanes/node, 8 feat/lane ----------------
// out[d][:] = b + dis[d] * ( g[d][:] + sum_e g[src][:] )

__global__ void pull1_k(const __half* __restrict__ g, const int* __restrict__ rowoff,
                        const int* __restrict__ deg, const int* __restrict__ csr,
                        const float* __restrict__ dis, const float* __restrict__ b,
                        float* __restrict__ out, int n_nodes) {
    int gt = blockIdx.x * blockDim.x + threadIdx.x;
    int node = gt >> 4;
    int f0 = (gt & 15) * 8;
    if (node >= n_nodes) return;
    int beg = rowoff[node];
    int end = beg + deg[node];
    float dd = dis[node];

    float acc[8];
    {
        F4H8 v; v.f = *(const float4*)(g + (size_t)node * 128 + f0);
        #pragma unroll
        for (int k = 0; k < 4; ++k) {
            float2 p = __half22float2(v.h[k]);
            acc[2 * k] = p.x; acc[2 * k + 1] = p.y;
        }
    }

    int j = beg;
    for (; j + 2 <= end; j += 2) {
        int s0 = csr[j];
        int s1 = csr[j + 1];
        F4H8 v0; v0.f = *(const float4*)(g + (size_t)s0 * 128 + f0);
        F4H8 v1; v1.f = *(const float4*)(g + (size_t)s1 * 128 + f0);
        #pragma unroll
        for (int k = 0; k < 4; ++k) {
            float2 p0 = __half22float2(v0.h[k]);
            float2 p1 = __half22float2(v1.h[k]);
            acc[2 * k]     += p0.x + p1.x;
            acc[2 * k + 1] += p0.y + p1.y;
        }
    }
    if (j < end) {
        int s = csr[j];
        F4H8 v; v.f = *(const float4*)(g + (size_t)s * 128 + f0);
        #pragma unroll
        for (int k = 0; k < 4; ++k) {
            float2 p = __half22float2(v.h[k]);
            acc[2 * k] += p.x; acc[2 * k + 1] += p.y;
        }
    }

    float* o = out + (size_t)node * 128 + f0;
    float4 b0 = *(const float4*)(b + f0);
    float4 b1 = *(const float4*)(b + f0 + 4);
    *(float4*)o = make_float4(b0.x + dd * acc[0], b0.y + dd * acc[1],
                              b0.z + dd * acc[2], b0.w + dd * acc[3]);
    *(float4*)(o + 4) = make_float4(b1.x + dd * acc[4], b1.y + dd * acc[5],
                                    b1.z + dd * acc[6], b1.w + dd * acc[7]);
}

// ---------------- pull2 (fp32 g, 32-wide): 8 lanes/node, 4 feat/lane ----------------

__global__ void pull2_k(const float* __restrict__ g, const int* __restrict__ rowoff,
                        const int* __restrict__ deg, const int* __restrict__ csr,
                        const float* __restrict__ dis, const float* __restrict__ b,
                        float* __restrict__ out, int n_nodes) {
    int gt = blockIdx.x * blockDim.x + threadIdx.x;
    int node = gt >> 3;
    int f0 = (gt & 7) * 4;
    if (node >= n_nodes) return;
    int beg = rowoff[node];
    int end = beg + deg[node];
    float dd = dis[node];

    float4 acc = *(const float4*)(g + (size_t)node * 32 + f0);

    int j = beg;
    for (; j + 2 <= end; j += 2) {
        int s0 = csr[j];
        int s1 = csr[j + 1];
        float4 h0 = *(const float4*)(g + (size_t)s0 * 32 + f0);
        float4 h1 = *(const float4*)(g + (size_t)s1 * 32 + f0);
        acc.x += h0.x + h1.x;
        acc.y += h0.y + h1.y;
        acc.z += h0.z + h1.z;
        acc.w += h0.w + h1.w;
    }
    if (j < end) {
        int s = csr[j];
        float4 hs = *(const float4*)(g + (size_t)s * 32 + f0);
        acc.x += hs.x; acc.y += hs.y; acc.z += hs.z; acc.w += hs.w;
    }

    float4 bb = *(const float4*)(b + f0);
    *(float4*)(out + (size_t)node * 32 + f0) =
        make_float4(bb.x + dd * acc.x, bb.y + dd * acc.y,
                    bb.z + dd * acc.z, bb.w + dd * acc.w);
}

// ---------------- fused pull3 + head (sel nodes only): 8 lanes/sel-entry ----------------

__global__ void pull_head_k(const float* __restrict__ g, const int* __restrict__ rowoff,
                            const int* __restrict__ deg, const int* __restrict__ csr,
                            const float* __restrict__ dis, const float* __restrict__ b3,
                            const int* __restrict__ sel, const float* __restrict__ Wl,
                            const float* __restrict__ bl, float* __restrict__ out, int n_sel) {
    int gt = blockIdx.x * blockDim.x + threadIdx.x;
    int t = gt >> 3;
    int f0 = (gt & 7) * 4;
    if (t >= n_sel) return;
    int node = sel[t];
    int beg = rowoff[node];
    int end = beg + deg[node];
    float dd = dis[node];

    float4 acc = *(const float4*)(g + (size_t)node * 32 + f0);

    int j = beg;
    for (; j + 2 <= end; j += 2) {
        int s0 = csr[j];
        int s1 = csr[j + 1];
        float4 h0 = *(const float4*)(g + (size_t)s0 * 32 + f0);
        float4 h1 = *(const float4*)(g + (size_t)s1 * 32 + f0);
        acc.x += h0.x + h1.x;
        acc.y += h0.y + h1.y;
        acc.z += h0.z + h1.z;
        acc.w += h0.w + h1.w;
    }
    if (j < end) {
        int s = csr[j];
        float4 hs = *(const float4*)(g + (size_t)s * 32 + f0);
        acc.x += hs.x; acc.y += hs.y; acc.z += hs.z; acc.w += hs.w;
    }

    float4 bb = *(const float4*)(b3 + f0);
    float a0 = bb.x + dd * acc.x;
    float a1 = bb.y + dd * acc.y;
    float a2 = bb.z + dd * acc.z;
    float a3 = bb.w + dd * acc.w;

    float l0 = a0 * Wl[(f0 + 0) * 2] + a1 * Wl[(f0 + 1) * 2]
             + a2 * Wl[(f0 + 2) * 2] + a3 * Wl[(f0 + 3) * 2];
    float l1 = a0 * Wl[(f0 + 0) * 2 + 1] + a1 * Wl[(f0 + 1) * 2 + 1]
             + a2 * Wl[(f0 + 2) * 2 + 1] + a3 * Wl[(f0 + 3) * 2 + 1];
    #pragma unroll
    for (int m = 1; m < 8; m <<= 1) {
        l0 += __shfl_xor(l0, m);
        l1 += __shfl_xor(l1, m);
    }
    if ((gt & 7) == 0) {
        l0 += bl[0]; l1 += bl[1];
        float mx = fmaxf(l0, l1);
        float e0 = expf(l0 - mx), e1 = expf(l1 - mx);
        float s = e0 + e1;
        float ls = logf(s);
        *(float2*)(out + (size_t)t * 2) = make_float2((l0 - mx) - ls, (l1 - mx) - ls);
        *(float2*)(out + 2 * (size_t)n_sel + (size_t)t * 2) = make_float2(e0 / s, e1 / s);
    }
}

// ---------------- launch ----------------

extern "C" void kernel_launch(void* const* d_in, const int* in_sizes, int n_in,
                              void* d_out, int out_size, void* d_ws, size_t ws_size,
                              hipStream_t stream) {
    const float* x  = (const float*)d_in[0];
    const int* edge = (const int*)d_in[1];
    const int* sel  = (const int*)d_in[2];
    const float* W1 = (const float*)d_in[4];
    const float* b1 = (const float*)d_in[5];
    const float* W2 = (const float*)d_in[6];
    const float* b2 = (const float*)d_in[7];
    const float* W3 = (const float*)d_in[8];
    const float* b3 = (const float*)d_in[9];
    const float* Wl = (const float*)d_in[10];
    const float* bl = (const float*)d_in[11];
    float* out = (float*)d_out;

    const int n_nodes = in_sizes[0] / F_IN;
    const int n_edges = in_sizes[1] / 2;
    const int n_sel   = in_sizes[2];
    const int* srcv = edge;
    const int* dstv = edge + n_edges;
    const int n_buckets = (n_nodes + NPB - 1) / NPB;

    char* ws = (char*)d_ws;
    int*      deg      = (int*)ws;      ws += alignup((size_t)n_nodes * 4);
    float*    dis      = (float*)ws;    ws += alignup((size_t)n_nodes * 4);
    int*      rowoff   = (int*)ws;      ws += alignup((size_t)n_nodes * 4);
    int*      bcur     = (int*)ws;      ws += alignup((size_t)n_buckets * 4);
    int*      partials = (int*)ws;      ws += alignup(1024);
    unsigned* tmp      = (unsigned*)ws; ws += alignup((size_t)n_edges * 4);
    int*      csr      = (int*)ws;      ws += alignup((size_t)n_edges * 4);
    char*     bufA     = ws;            ws += alignup((size_t)n_nodes * HID * 4);
    float*    bufB     = (float*)ws;

    const int B = 256;
    #define GRD(n) (((n) + B - 1) / B)
    const int nblk = GRD(n_nodes);

    // degree + scan + CSR build (reused by all 3 layers)
    hipMemsetAsync(deg, 0, (size_t)n_nodes * 4, stream);
    deg_count_k<<<GRD(n_edges), B, 0, stream>>>(dstv, deg, n_edges);
    scan_block_k<<<nblk, B, 0, stream>>>(deg, rowoff, partials, n_nodes);
    scan_partials_k<<<1, B, 0, stream>>>(partials, nblk);
    add_offsets_k<<<nblk, B, 0, stream>>>(deg, dis, rowoff, bcur, partials, n_nodes);
    binA_k<<<GRD(n_edges), B, 0, stream>>>(srcv, dstv, bcur, tmp, n_edges);
    binB_k<<<n_buckets, B, 0, stream>>>(tmp, rowoff, csr, n_nodes, n_edges);

    const int gemm_blocks = (n_nodes + 63) / 64;

    // layer 1: g1 (fp16) = dis * (x @ W1); agg1 = b1 + dis*(g1 + gather)
    gemm1_k<<<gemm_blocks, B, 0, stream>>>(x, W1, dis, (__half*)bufA, n_nodes);
    pull1_k<<<GRD(n_nodes * 16), B, 0, stream>>>((const __half*)bufA, rowoff, deg, csr, dis, b1, bufB, n_nodes);

    // layer 2
    gemm2_k<<<gemm_blocks, B, 0, stream>>>(bufB, W2, dis, (float*)bufA, n_nodes);
    pull2_k<<<GRD(n_nodes * 8), B, 0, stream>>>((const float*)bufA, rowoff, deg, csr, dis, b2, bufB, n_nodes);

    // layer 3: g3 for all nodes; pull+head only for sel nodes
    gemm3_k<<<gemm_blocks, B, 0, stream>>>(bufB, W3, dis, (float*)bufA, n_nodes);
    pull_head_k<<<GRD(n_sel * 8), B, 0, stream>>>((const float*)bufA, rowoff, deg, csr, dis, b3,
                                                  sel, Wl, bl, out, n_sel);

    #undef GRD
}

// Round 6
// 206.438 us; speedup vs baseline: 1.7886x; 1.7886x over previous
//
#include <hip/hip_runtime.h>
#include <hip/hip_fp16.h>

#define F_IN 128
#define HID 128
#define HID4 32
#define NPB 64           // nodes per CSR bucket
#define SRC_BITS 17      // n_nodes = 50000 < 2^17
#define NB 64            // partition blocks (n_buckets*NB must be <= 65536)
#define MAXBUCKET 1024   // LDS counter array size (n_buckets = 782)

static inline size_t alignup(size_t x) { return (x + 255) & ~(size_t)255; }

union H4 { uint2 u; __half2 h[2]; };      // 4 halfs = 8 B
union F4H8 { float4 f; __half2 h[4]; };   // 8 halfs = 16 B

// ---------------- pass 1: per-node degree (global, 16 ops/addr) + per-block bucket histogram ----------------

__global__ __launch_bounds__(256) void degh_k(const int* __restrict__ dst, int* __restrict__ deg,
                                              int* __restrict__ ghist, int ne, int n_buckets) {
    __shared__ int h[MAXBUCKET];
    const int t = threadIdx.x;
    for (int b = t; b < n_buckets; b += 256) h[b] = 0;
    __syncthreads();
    const int chunk = (ne + NB - 1) / NB;
    const int beg = blockIdx.x * chunk;
    const int end = min(ne, beg + chunk);
    for (int e = beg + t; e < end; e += 256) {
        int d = dst[e];
        atomicAdd(&deg[d], 1);        // ~16 ops/address: throughput-fine
        atomicAdd(&h[d / NPB], 1);    // LDS atomic: contention-cheap
    }
    __syncthreads();
    for (int b = t; b < n_buckets; b += 256)
        ghist[(size_t)b * NB + blockIdx.x] = h[b];   // [bucket][block] for flat scan
}

// ---------------- generic 2-level exclusive scan ----------------

__global__ void scan_block_k(const int* __restrict__ in, int* __restrict__ out,
                             int* __restrict__ partials, int n) {
    __shared__ int tmp[256];
    int i = blockIdx.x * 256 + threadIdx.x;
    int v = (i < n) ? in[i] : 0;
    tmp[threadIdx.x] = v;
    __syncthreads();
    for (int off = 1; off < 256; off <<= 1) {
        int t = (threadIdx.x >= off) ? tmp[threadIdx.x - off] : 0;
        __syncthreads();
        tmp[threadIdx.x] += t;
        __syncthreads();
    }
    if (i < n) out[i] = tmp[threadIdx.x] - v;
    if (threadIdx.x == 255) partials[blockIdx.x] = tmp[255];
}

__global__ void scan_partials_k(int* __restrict__ partials, int nb) {
    __shared__ int tmp[256];
    int v = (threadIdx.x < nb) ? partials[threadIdx.x] : 0;
    tmp[threadIdx.x] = v;
    __syncthreads();
    for (int off = 1; off < 256; off <<= 1) {
        int t = (threadIdx.x >= off) ? tmp[threadIdx.x - off] : 0;
        __syncthreads();
        tmp[threadIdx.x] += t;
        __syncthreads();
    }
    if (threadIdx.x < nb) partials[threadIdx.x] = tmp[threadIdx.x] - v;
}

// finalize rowoff, compute dis
__global__ void add_offsets_k(const int* __restrict__ deg, float* __restrict__ dis,
                              int* __restrict__ rowoff, const int* __restrict__ partials, int n) {
    int i = blockIdx.x * 256 + threadIdx.x;
    if (i < n) {
        rowoff[i] += partials[i >> 8];
        dis[i] = rsqrtf((float)(deg[i] + 1));
    }
}

// finalize goff
__global__ void add2_k(int* __restrict__ goff, const int* __restrict__ partials, int n) {
    int i = blockIdx.x * 256 + threadIdx.x;
    if (i < n) goff[i] += partials[i >> 8];
}

// ---------------- pass 2: partition edges into bucket-ordered tmp (LDS cursors only) ----------------

__global__ __launch_bounds__(256) void scatter2_k(const int* __restrict__ src, const int* __restrict__ dst,
                                                  const int* __restrict__ goff,
                                                  unsigned* __restrict__ tmp, int ne, int n_buckets) {
    __shared__ int cur[MAXBUCKET];
    const int t = threadIdx.x;
    for (int b = t; b < n_buckets; b += 256)
        cur[b] = goff[(size_t)b * NB + blockIdx.x];
    __syncthreads();
    const int chunk = (ne + NB - 1) / NB;
    const int beg = blockIdx.x * chunk;
    const int end = min(ne, beg + chunk);
    for (int e = beg + t; e < end; e += 256) {
        int d = dst[e];
        int s = src[e];
        int pos = atomicAdd(&cur[d / NPB], 1);   // LDS atomic
        tmp[pos] = ((unsigned)(d & (NPB - 1)) << SRC_BITS) | (unsigned)s;
    }
}

// ---------------- pass 3: order within bucket into final CSR ----------------

__global__ __launch_bounds__(256) void binB_k(const unsigned* __restrict__ tmp,
                                              const int* __restrict__ rowoff,
                                              int* __restrict__ csr, int n_nodes, int ne) {
    __shared__ int cnt[NPB];
    __shared__ int roff_s[NPB];
    const int t = threadIdx.x;
    const int base = blockIdx.x * NPB;
    if (t < NPB) {
        cnt[t] = 0;
        int idx = base + t;
        roff_s[t] = (idx < n_nodes) ? rowoff[idx] : ne;
    }
    __syncthreads();
    int beg = roff_s[0];
    int end = (base + NPB < n_nodes) ? rowoff[base + NPB] : ne;
    for (int j = beg + t; j < end; j += 256) {
        unsigned e = tmp[j];
        int ld = e >> SRC_BITS;
        int s  = e & ((1u << SRC_BITS) - 1);
        int pos = roff_s[ld] + atomicAdd(&cnt[ld], 1);
        csr[pos] = s;
    }
}

// ---------------- GEMM1: g[n][128] (fp16) = dis[n] * (in[n][128] @ W[128][128]) ----------------

__global__ __launch_bounds__(256) void gemm1_k(const float* __restrict__ in,
                                               const float* __restrict__ W,
                                               const float* __restrict__ dis,
                                               __half* __restrict__ hout, int n_rows) {
    __shared__ float xs[64][132];
    __shared__ float wt[32][128];
    const int t = threadIdx.x;
    const int row0 = blockIdx.x * 64;

    #pragma unroll
    for (int i = 0; i < 8; ++i) {
        int q = t + i * 256;
        int row = q >> 5, c4 = (q & 31) * 4;
        float4 v = make_float4(0.f, 0.f, 0.f, 0.f);
        if (row0 + row < n_rows) v = *(const float4*)(in + (size_t)(row0 + row) * 128 + c4);
        *(float4*)&xs[row][c4] = v;
    }

    const int c4a = (t & 15) * 4;
    const int r4 = (t >> 4) * 4;

    float acc[4][8];
    #pragma unroll
    for (int i = 0; i < 4; ++i)
        #pragma unroll
        for (int j = 0; j < 8; ++j) acc[i][j] = 0.f;

    for (int kt = 0; kt < 4; ++kt) {
        __syncthreads();
        #pragma unroll
        for (int i = 0; i < 4; ++i) {
            int q = t + i * 256;
            int kk = q >> 5, c4 = (q & 31) * 4;
            *(float4*)&wt[kk][c4] = *(const float4*)(W + (size_t)(kt * 32 + kk) * 128 + c4);
        }
        __syncthreads();
        #pragma unroll 4
        for (int k = 0; k < 32; ++k) {
            float xv[4];
            #pragma unroll
            for (int i = 0; i < 4; ++i) xv[i] = xs[r4 + i][kt * 32 + k];
            float4 w0 = *(float4*)&wt[k][c4a];
            float4 w1 = *(float4*)&wt[k][64 + c4a];
            #pragma unroll
            for (int i = 0; i < 4; ++i) {
                acc[i][0] += xv[i] * w0.x; acc[i][1] += xv[i] * w0.y;
                acc[i][2] += xv[i] * w0.z; acc[i][3] += xv[i] * w0.w;
                acc[i][4] += xv[i] * w1.x; acc[i][5] += xv[i] * w1.y;
                acc[i][6] += xv[i] * w1.z; acc[i][7] += xv[i] * w1.w;
            }
        }
    }

    #pragma unroll
    for (int i = 0; i < 4; ++i) {
        int row = row0 + r4 + i;
        if (row < n_rows) {
            float sc = dis[row];
            __half* p = hout + (size_t)row * 128;
            H4 a, b;
            a.h[0] = __floats2half2_rn(sc * acc[i][0], sc * acc[i][1]);
            a.h[1] = __floats2half2_rn(sc * acc[i][2], sc * acc[i][3]);
            b.h[0] = __floats2half2_rn(sc * acc[i][4], sc * acc[i][5]);
            b.h[1] = __floats2half2_rn(sc * acc[i][6], sc * acc[i][7]);
            *(uint2*)(p + c4a) = a.u;
            *(uint2*)(p + 64 + c4a) = b.u;
        }
    }
}

// ---------------- GEMM2: g[n][32] = dis[n] * (relu(in[n][128]) @ W[128][32]) ----------------

__global__ __launch_bounds__(256) void gemm2_k(const float* __restrict__ in,
                                               const float* __restrict__ W,
                                               const float* __restrict__ dis,
                                               float* __restrict__ out, int n_rows) {
    __shared__ float xs[64][132];
    __shared__ float wt[128][32];
    const int t = threadIdx.x;
    const int row0 = blockIdx.x * 64;

    #pragma unroll
    for (int i = 0; i < 8; ++i) {
        int q = t + i * 256;
        int row = q >> 5, c4 = (q & 31) * 4;
        float4 v = make_float4(0.f, 0.f, 0.f, 0.f);
        if (row0 + row < n_rows) {
            v = *(const float4*)(in + (size_t)(row0 + row) * 128 + c4);
            v.x = fmaxf(v.x, 0.f); v.y = fmaxf(v.y, 0.f);
            v.z = fmaxf(v.z, 0.f); v.w = fmaxf(v.w, 0.f);
        }
        *(float4*)&xs[row][c4] = v;
    }
    #pragma unroll
    for (int i = 0; i < 4; ++i) {
        int q = t + i * 256;
        int kk = q >> 3, c4 = (q & 7) * 4;
        *(float4*)&wt[kk][c4] = *(const float4*)(W + (size_t)kk * 32 + c4);
    }
    __syncthreads();

    const int c4 = (t & 7) * 4;
    const int r2 = (t >> 3) * 2;

    float acc[2][4];
    #pragma unroll
    for (int i = 0; i < 2; ++i)
        #pragma unroll
        for (int j = 0; j < 4; ++j) acc[i][j] = 0.f;

    #pragma unroll 4
    for (int k = 0; k < 128; ++k) {
        float x0 = xs[r2][k], x1 = xs[r2 + 1][k];
        float4 w = *(float4*)&wt[k][c4];
        acc[0][0] += x0 * w.x; acc[0][1] += x0 * w.y; acc[0][2] += x0 * w.z; acc[0][3] += x0 * w.w;
        acc[1][0] += x1 * w.x; acc[1][1] += x1 * w.y; acc[1][2] += x1 * w.z; acc[1][3] += x1 * w.w;
    }

    #pragma unroll
    for (int i = 0; i < 2; ++i) {
        int row = row0 + r2 + i;
        if (row < n_rows) {
            float sc = dis[row];
            *(float4*)(out + (size_t)row * 32 + c4) =
                make_float4(sc * acc[i][0], sc * acc[i][1], sc * acc[i][2], sc * acc[i][3]);
        }
    }
}

// ---------------- GEMM3: g[n][32] = dis[n] * (relu(in[n][32]) @ W[32][32]) ----------------

__global__ __launch_bounds__(256) void gemm3_k(const float* __restrict__ in,
                                               const float* __restrict__ W,
                                               const float* __restrict__ dis,
                                               float* __restrict__ out, int n_rows) {
    __shared__ float xs[64][36];
    __shared__ float wt[32][32];
    const int t = threadIdx.x;
    const int row0 = blockIdx.x * 64;

    #pragma unroll
    for (int i = 0; i < 2; ++i) {
        int q = t + i * 256;
        int row = q >> 3, c4 = (q & 7) * 4;
        float4 v = make_float4(0.f, 0.f, 0.f, 0.f);
        if (row0 + row < n_rows) {
            v = *(const float4*)(in + (size_t)(row0 + row) * 32 + c4);
            v.x = fmaxf(v.x, 0.f); v.y = fmaxf(v.y, 0.f);
            v.z = fmaxf(v.z, 0.f); v.w = fmaxf(v.w, 0.f);
        }
        *(float4*)&xs[row][c4] = v;
    }
    {
        int kk = t >> 3, c4 = (t & 7) * 4;
        *(float4*)&wt[kk][c4] = *(const float4*)(W + (size_t)kk * 32 + c4);
    }
    __syncthreads();

    const int c4 = (t & 7) * 4;
    const int r2 = (t >> 3) * 2;

    float acc[2][4];
    #pragma unroll
    for (int i = 0; i < 2; ++i)
        #pragma unroll
        for (int j = 0; j < 4; ++j) acc[i][j] = 0.f;

    #pragma unroll
    for (int k = 0; k < 32; ++k) {
        float x0 = xs[r2][k], x1 = xs[r2 + 1][k];
        float4 w = *(float4*)&wt[k][c4];
        acc[0][0] += x0 * w.x; acc[0][1] += x0 * w.y; acc[0][2] += x0 * w.z; acc[0][3] += x0 * w.w;
        acc[1][0] += x1 * w.x; acc[1][1] += x1 * w.y; acc[1][2] += x1 * w.z; acc[1][3] += x1 * w.w;
    }

    #pragma unroll
    for (int i = 0; i < 2; ++i) {
        int row = row0 + r2 + i;
        if (row < n_rows) {
            float sc = dis[row];
            *(float4*)(out + (size_t)row * 32 + c4) =
                make_float4(sc * acc[i][0], sc * acc[i][1], sc * acc[i][2], sc * acc[i][3]);
        }
    }
}

// ---------------- pull1 (fp16 g, 128-wide): 16 lanes/node, 8 feat/lane ----------------
// out[d][:] = b + dis[d] * ( g[d][:] + sum_e g[src][:] )

__global__ void pull1_k(const __half* __restrict__ g, const int* __restrict__ rowoff,
                        const int* __restrict__ deg, const int* __restrict__ csr,
                        const float* __restrict__ dis, const float* __restrict__ b,
                        float* __restrict__ out, int n_nodes) {
    int gt = blockIdx.x * blockDim.x + threadIdx.x;
    int node = gt >> 4;
    int f0 = (gt & 15) * 8;
    if (node >= n_nodes) return;
    int beg = rowoff[node];
    int end = beg + deg[node];
    float dd = dis[node];

    float acc[8];
    {
        F4H8 v; v.f = *(const float4*)(g + (size_t)node * 128 + f0);
        #pragma unroll
        for (int k = 0; k < 4; ++k) {
            float2 p = __half22float2(v.h[k]);
            acc[2 * k] = p.x; acc[2 * k + 1] = p.y;
        }
    }

    int j = beg;
    for (; j + 2 <= end; j += 2) {
        int s0 = csr[j];
        int s1 = csr[j + 1];
        F4H8 v0; v0.f = *(const float4*)(g + (size_t)s0 * 128 + f0);
        F4H8 v1; v1.f = *(const float4*)(g + (size_t)s1 * 128 + f0);
        #pragma unroll
        for (int k = 0; k < 4; ++k) {
            float2 p0 = __half22float2(v0.h[k]);
            float2 p1 = __half22float2(v1.h[k]);
            acc[2 * k]     += p0.x + p1.x;
            acc[2 * k + 1] += p0.y + p1.y;
        }
    }
    if (j < end) {
        int s = csr[j];
        F4H8 v; v.f = *(const float4*)(g + (size_t)s * 128 + f0);
        #pragma unroll
        for (int k = 0; k < 4; ++k) {
            float2 p = __half22float2(v.h[k]);
            acc[2 * k] += p.x; acc[2 * k + 1] += p.y;
        }
    }

    float* o = out + (size_t)node * 128 + f0;
    float4 b0 = *(const float4*)(b + f0);
    float4 b1 = *(const float4*)(b + f0 + 4);
    *(float4*)o = make_float4(b0.x + dd * acc[0], b0.y + dd * acc[1],
                              b0.z + dd * acc[2], b0.w + dd * acc[3]);
    *(float4*)(o + 4) = make_float4(b1.x + dd * acc[4], b1.y + dd * acc[5],
                                    b1.z + dd * acc[6], b1.w + dd * acc[7]);
}

// ---------------- pull2 (fp32 g, 32-wide): 8 lanes/node, 4 feat/lane ----------------

__global__ void pull2_k(const float* __restrict__ g, const int* __restrict__ rowoff,
                        const int* __restrict__ deg, const int* __restrict__ csr,
                        const float* __restrict__ dis, const float* __restrict__ b,
                        float* __restrict__ out, int n_nodes) {
    int gt = blockIdx.x * blockDim.x + threadIdx.x;
    int node = gt >> 3;
    int f0 = (gt & 7) * 4;
    if (node >= n_nodes) return;
    int beg = rowoff[node];
    int end = beg + deg[node];
    float dd = dis[node];

    float4 acc = *(const float4*)(g + (size_t)node * 32 + f0);

    int j = beg;
    for (; j + 2 <= end; j += 2) {
        int s0 = csr[j];
        int s1 = csr[j + 1];
        float4 h0 = *(const float4*)(g + (size_t)s0 * 32 + f0);
        float4 h1 = *(const float4*)(g + (size_t)s1 * 32 + f0);
        acc.x += h0.x + h1.x;
        acc.y += h0.y + h1.y;
        acc.z += h0.z + h1.z;
        acc.w += h0.w + h1.w;
    }
    if (j < end) {
        int s = csr[j];
        float4 hs = *(const float4*)(g + (size_t)s * 32 + f0);
        acc.x += hs.x; acc.y += hs.y; acc.z += hs.z; acc.w += hs.w;
    }

    float4 bb = *(const float4*)(b + f0);
    *(float4*)(out + (size_t)node * 32 + f0) =
        make_float4(bb.x + dd * acc.x, bb.y + dd * acc.y,
                    bb.z + dd * acc.z, bb.w + dd * acc.w);
}

// ---------------- fused pull3 + head (sel nodes only): 8 lanes/sel-entry ----------------

__global__ void pull_head_k(const float* __restrict__ g, const int* __restrict__ rowoff,
                            const int* __restrict__ deg, const int* __restrict__ csr,
                            const float* __restrict__ dis, const float* __restrict__ b3,
                            const int* __restrict__ sel, const float* __restrict__ Wl,
                            const float* __restrict__ bl, float* __restrict__ out, int n_sel) {
    int gt = blockIdx.x * blockDim.x + threadIdx.x;
    int t = gt >> 3;
    int f0 = (gt & 7) * 4;
    if (t >= n_sel) return;
    int node = sel[t];
    int beg = rowoff[node];
    int end = beg + deg[node];
    float dd = dis[node];

    float4 acc = *(const float4*)(g + (size_t)node * 32 + f0);

    int j = beg;
    for (; j + 2 <= end; j += 2) {
        int s0 = csr[j];
        int s1 = csr[j + 1];
        float4 h0 = *(const float4*)(g + (size_t)s0 * 32 + f0);
        float4 h1 = *(const float4*)(g + (size_t)s1 * 32 + f0);
        acc.x += h0.x + h1.x;
        acc.y += h0.y + h1.y;
        acc.z += h0.z + h1.z;
        acc.w += h0.w + h1.w;
    }
    if (j < end) {
        int s = csr[j];
        float4 hs = *(const float4*)(g + (size_t)s * 32 + f0);
        acc.x += hs.x; acc.y += hs.y; acc.z += hs.z; acc.w += hs.w;
    }

    float4 bb = *(const float4*)(b3 + f0);
    float a0 = bb.x + dd * acc.x;
    float a1 = bb.y + dd * acc.y;
    float a2 = bb.z + dd * acc.z;
    float a3 = bb.w + dd * acc.w;

    float l0 = a0 * Wl[(f0 + 0) * 2] + a1 * Wl[(f0 + 1) * 2]
             + a2 * Wl[(f0 + 2) * 2] + a3 * Wl[(f0 + 3) * 2];
    float l1 = a0 * Wl[(f0 + 0) * 2 + 1] + a1 * Wl[(f0 + 1) * 2 + 1]
             + a2 * Wl[(f0 + 2) * 2 + 1] + a3 * Wl[(f0 + 3) * 2 + 1];
    #pragma unroll
    for (int m = 1; m < 8; m <<= 1) {
        l0 += __shfl_xor(l0, m);
        l1 += __shfl_xor(l1, m);
    }
    if ((gt & 7) == 0) {
        l0 += bl[0]; l1 += bl[1];
        float mx = fmaxf(l0, l1);
        float e0 = expf(l0 - mx), e1 = expf(l1 - mx);
        float s = e0 + e1;
        float ls = logf(s);
        *(float2*)(out + (size_t)t * 2) = make_float2((l0 - mx) - ls, (l1 - mx) - ls);
        *(float2*)(out + 2 * (size_t)n_sel + (size_t)t * 2) = make_float2(e0 / s, e1 / s);
    }
}

// ---------------- launch ----------------

extern "C" void kernel_launch(void* const* d_in, const int* in_sizes, int n_in,
                              void* d_out, int out_size, void* d_ws, size_t ws_size,
                              hipStream_t stream) {
    const float* x  = (const float*)d_in[0];
    const int* edge = (const int*)d_in[1];
    const int* sel  = (const int*)d_in[2];
    const float* W1 = (const float*)d_in[4];
    const float* b1 = (const float*)d_in[5];
    const float* W2 = (const float*)d_in[6];
    const float* b2 = (const float*)d_in[7];
    const float* W3 = (const float*)d_in[8];
    const float* b3 = (const float*)d_in[9];
    const float* Wl = (const float*)d_in[10];
    const float* bl = (const float*)d_in[11];
    float* out = (float*)d_out;

    const int n_nodes = in_sizes[0] / F_IN;
    const int n_edges = in_sizes[1] / 2;
    const int n_sel   = in_sizes[2];
    const int* srcv = edge;
    const int* dstv = edge + n_edges;
    const int n_buckets = (n_nodes + NPB - 1) / NPB;   // 782
    const int n_gh = n_buckets * NB;                   // 50048 <= 65536

    char* ws = (char*)d_ws;
    int*      deg      = (int*)ws;      ws += alignup((size_t)n_nodes * 4);
    float*    dis      = (float*)ws;    ws += alignup((size_t)n_nodes * 4);
    int*      rowoff   = (int*)ws;      ws += alignup((size_t)n_nodes * 4);
    int*      ghist    = (int*)ws;      ws += alignup((size_t)n_gh * 4);
    int*      goff     = (int*)ws;      ws += alignup((size_t)n_gh * 4);
    int*      partials = (int*)ws;      ws += alignup(1024);
    int*      partial2 = (int*)ws;      ws += alignup(1024);
    unsigned* tmp      = (unsigned*)ws; ws += alignup((size_t)n_edges * 4);
    int*      csr      = (int*)ws;      ws += alignup((size_t)n_edges * 4);
    char*     bufA     = ws;            ws += alignup((size_t)n_nodes * HID * 4);
    float*    bufB     = (float*)ws;

    const int B = 256;
    #define GRD(n) (((n) + B - 1) / B)
    const int nblk  = GRD(n_nodes);
    const int nblk2 = GRD(n_gh);

    // degree + bucket histogram
    hipMemsetAsync(deg, 0, (size_t)n_nodes * 4, stream);
    degh_k<<<NB, B, 0, stream>>>(dstv, deg, ghist, n_edges, n_buckets);
    // scan deg -> rowoff (+dis)
    scan_block_k<<<nblk, B, 0, stream>>>(deg, rowoff, partials, n_nodes);
    scan_partials_k<<<1, B, 0, stream>>>(partials, nblk);
    add_offsets_k<<<nblk, B, 0, stream>>>(deg, dis, rowoff, partials, n_nodes);
    // scan ghist -> goff
    scan_block_k<<<nblk2, B, 0, stream>>>(ghist, goff, partial2, n_gh);
    scan_partials_k<<<1, B, 0, stream>>>(partial2, nblk2);
    add2_k<<<nblk2, B, 0, stream>>>(goff, partial2, n_gh);
    // partition + final CSR
    scatter2_k<<<NB, B, 0, stream>>>(srcv, dstv, goff, tmp, n_edges, n_buckets);
    binB_k<<<n_buckets, B, 0, stream>>>(tmp, rowoff, csr, n_nodes, n_edges);

    const int gemm_blocks = (n_nodes + 63) / 64;

    // layer 1: g1 (fp16) = dis * (x @ W1); agg1 = b1 + dis*(g1 + gather)
    gemm1_k<<<gemm_blocks, B, 0, stream>>>(x, W1, dis, (__half*)bufA, n_nodes);
    pull1_k<<<GRD(n_nodes * 16), B, 0, stream>>>((const __half*)bufA, rowoff, deg, csr, dis, b1, bufB, n_nodes);

    // layer 2
    gemm2_k<<<gemm_blocks, B, 0, stream>>>(bufB, W2, dis, (float*)bufA, n_nodes);
    pull2_k<<<GRD(n_nodes * 8), B, 0, stream>>>((const float*)bufA, rowoff, deg, csr, dis, b2, bufB, n_nodes);

    // layer 3: g3 for all nodes; pull+head only for sel nodes
    gemm3_k<<<gemm_blocks, B, 0, stream>>>(bufB, W3, dis, (float*)bufA, n_nodes);
    pull_head_k<<<GRD(n_sel * 8), B, 0, stream>>>((const float*)bufA, rowoff, deg, csr, dis, b3,
                                                  sel, Wl, bl, out, n_sel);

    #undef GRD
}

// Round 7
// 153.651 us; speedup vs baseline: 2.4031x; 1.3435x over previous
//
#include <hip/hip_runtime.h>
#include <hip/hip_fp16.h>

#define F_IN 128
#define HID 128
#define HID4 32
#define NPB 256          // nodes per CSR bucket
#define SRC_BITS 17      // n_nodes = 50000 < 2^17 ; (d % NPB) << 17 fits 32b
#define NBK 256          // partition chunks/blocks (n_buckets*NBK <= 65536 for 2-level scan)
#define MAXBUCKET 256    // LDS counter array size (n_buckets = 196)

static inline size_t alignup(size_t x) { return (x + 255) & ~(size_t)255; }

union H4 { uint2 u; __half2 h[2]; };      // 4 halfs = 8 B
union F4H8 { float4 f; __half2 h[4]; };   // 8 halfs = 16 B

// ---------------- pass 1: per-(block,bucket) histogram, LDS only ----------------

__global__ __launch_bounds__(1024) void hist_k(const int* __restrict__ dst,
                                               int* __restrict__ ghist, int ne, int n_buckets) {
    __shared__ int h[MAXBUCKET];
    const int t = threadIdx.x;
    for (int b = t; b < n_buckets; b += 1024) h[b] = 0;
    __syncthreads();
    const int chunk = (ne + NBK - 1) / NBK;
    const int beg = blockIdx.x * chunk;
    const int end = min(ne, beg + chunk);
    for (int e = beg + t; e < end; e += 1024)
        atomicAdd(&h[dst[e] / NPB], 1);           // LDS atomic
    __syncthreads();
    for (int b = t; b < n_buckets; b += 1024)
        ghist[(size_t)b * NBK + blockIdx.x] = h[b];  // bucket-major for flat scan
}

// ---------------- generic 2-level exclusive scan ----------------

__global__ void scan_block_k(const int* __restrict__ in, int* __restrict__ out,
                             int* __restrict__ partials, int n) {
    __shared__ int tmp[256];
    int i = blockIdx.x * 256 + threadIdx.x;
    int v = (i < n) ? in[i] : 0;
    tmp[threadIdx.x] = v;
    __syncthreads();
    for (int off = 1; off < 256; off <<= 1) {
        int t = (threadIdx.x >= off) ? tmp[threadIdx.x - off] : 0;
        __syncthreads();
        tmp[threadIdx.x] += t;
        __syncthreads();
    }
    if (i < n) out[i] = tmp[threadIdx.x] - v;
    if (threadIdx.x == 255) partials[blockIdx.x] = tmp[255];
}

__global__ void scan_partials_k(int* __restrict__ partials, int nb) {
    __shared__ int tmp[256];
    int v = (threadIdx.x < nb) ? partials[threadIdx.x] : 0;
    tmp[threadIdx.x] = v;
    __syncthreads();
    for (int off = 1; off < 256; off <<= 1) {
        int t = (threadIdx.x >= off) ? tmp[threadIdx.x - off] : 0;
        __syncthreads();
        tmp[threadIdx.x] += t;
        __syncthreads();
    }
    if (threadIdx.x < nb) partials[threadIdx.x] = tmp[threadIdx.x] - v;
}

__global__ void add2_k(int* __restrict__ goff, const int* __restrict__ partials, int n) {
    int i = blockIdx.x * 256 + threadIdx.x;
    if (i < n) goff[i] += partials[i >> 8];
}

// ---------------- pass 2: partition edges into bucket-ordered tmp (LDS cursors) ----------------

__global__ __launch_bounds__(1024) void scatter2_k(const int* __restrict__ src, const int* __restrict__ dst,
                                                   const int* __restrict__ goff,
                                                   unsigned* __restrict__ tmp, int ne, int n_buckets) {
    __shared__ int cur[MAXBUCKET];
    const int t = threadIdx.x;
    for (int b = t; b < n_buckets; b += 1024)
        cur[b] = goff[(size_t)b * NBK + blockIdx.x];
    __syncthreads();
    const int chunk = (ne + NBK - 1) / NBK;
    const int beg = blockIdx.x * chunk;
    const int end = min(ne, beg + chunk);
    for (int e = beg + t; e < end; e += 1024) {
        int d = dst[e];
        int s = src[e];
        int pos = atomicAdd(&cur[d / NPB], 1);    // LDS atomic
        tmp[pos] = ((unsigned)(d & (NPB - 1)) << SRC_BITS) | (unsigned)s;
    }
}

// ---------------- pass 3: per-bucket deg/dis/rowoff + final CSR placement ----------------

__global__ __launch_bounds__(NPB) void binC_k(const unsigned* __restrict__ tmp,
                                              const int* __restrict__ goff,
                                              int* __restrict__ deg, float* __restrict__ dis,
                                              int* __restrict__ rowoff, int* __restrict__ csr,
                                              int n_nodes, int ne, int n_buckets) {
    __shared__ int cnt[NPB];
    __shared__ int sc[NPB];
    const int t = threadIdx.x;
    const int bid = blockIdx.x;
    const int base = goff[(size_t)bid * NBK];
    const int end = (bid + 1 < n_buckets) ? goff[(size_t)(bid + 1) * NBK] : ne;

    cnt[t] = 0;
    __syncthreads();
    for (int j = base + t; j < end; j += NPB)
        atomicAdd(&cnt[tmp[j] >> SRC_BITS], 1);   // LDS atomic, per-node degree
    __syncthreads();

    int mydeg = cnt[t];
    sc[t] = mydeg;
    __syncthreads();
    for (int off = 1; off < NPB; off <<= 1) {     // Hillis-Steele inclusive scan
        int v = (t >= off) ? sc[t - off] : 0;
        __syncthreads();
        sc[t] += v;
        __syncthreads();
    }
    int excl = sc[t] - mydeg;
    int node = bid * NPB + t;
    if (node < n_nodes) {
        deg[node] = mydeg;
        dis[node] = rsqrtf((float)(mydeg + 1));
        rowoff[node] = base + excl;
    }
    cnt[t] = base + excl;                         // becomes placement cursor
    __syncthreads();
    for (int j = base + t; j < end; j += NPB) {
        unsigned e = tmp[j];
        int ld = e >> SRC_BITS;
        int s  = e & ((1u << SRC_BITS) - 1);
        int pos = atomicAdd(&cnt[ld], 1);
        csr[pos] = s;
    }
}

// ---------------- GEMM1: g[n][128] (fp16) = dis[n] * (in[n][128] @ W[128][128]) ----------------

__global__ __launch_bounds__(256) void gemm1_k(const float* __restrict__ in,
                                               const float* __restrict__ W,
                                               const float* __restrict__ dis,
                                               __half* __restrict__ hout, int n_rows) {
    __shared__ float xs[64][132];
    __shared__ float wt[32][128];
    const int t = threadIdx.x;
    const int row0 = blockIdx.x * 64;

    #pragma unroll
    for (int i = 0; i < 8; ++i) {
        int q = t + i * 256;
        int row = q >> 5, c4 = (q & 31) * 4;
        float4 v = make_float4(0.f, 0.f, 0.f, 0.f);
        if (row0 + row < n_rows) v = *(const float4*)(in + (size_t)(row0 + row) * 128 + c4);
        *(float4*)&xs[row][c4] = v;
    }

    const int c4a = (t & 15) * 4;
    const int r4 = (t >> 4) * 4;

    float acc[4][8];
    #pragma unroll
    for (int i = 0; i < 4; ++i)
        #pragma unroll
        for (int j = 0; j < 8; ++j) acc[i][j] = 0.f;

    for (int kt = 0; kt < 4; ++kt) {
        __syncthreads();
        #pragma unroll
        for (int i = 0; i < 4; ++i) {
            int q = t + i * 256;
            int kk = q >> 5, c4 = (q & 31) * 4;
            *(float4*)&wt[kk][c4] = *(const float4*)(W + (size_t)(kt * 32 + kk) * 128 + c4);
        }
        __syncthreads();
        #pragma unroll 4
        for (int k = 0; k < 32; ++k) {
            float xv[4];
            #pragma unroll
            for (int i = 0; i < 4; ++i) xv[i] = xs[r4 + i][kt * 32 + k];
            float4 w0 = *(float4*)&wt[k][c4a];
            float4 w1 = *(float4*)&wt[k][64 + c4a];
            #pragma unroll
            for (int i = 0; i < 4; ++i) {
                acc[i][0] += xv[i] * w0.x; acc[i][1] += xv[i] * w0.y;
                acc[i][2] += xv[i] * w0.z; acc[i][3] += xv[i] * w0.w;
                acc[i][4] += xv[i] * w1.x; acc[i][5] += xv[i] * w1.y;
                acc[i][6] += xv[i] * w1.z; acc[i][7] += xv[i] * w1.w;
            }
        }
    }

    #pragma unroll
    for (int i = 0; i < 4; ++i) {
        int row = row0 + r4 + i;
        if (row < n_rows) {
            float sc = dis[row];
            __half* p = hout + (size_t)row * 128;
            H4 a, b;
            a.h[0] = __floats2half2_rn(sc * acc[i][0], sc * acc[i][1]);
            a.h[1] = __floats2half2_rn(sc * acc[i][2], sc * acc[i][3]);
            b.h[0] = __floats2half2_rn(sc * acc[i][4], sc * acc[i][5]);
            b.h[1] = __floats2half2_rn(sc * acc[i][6], sc * acc[i][7]);
            *(uint2*)(p + c4a) = a.u;
            *(uint2*)(p + 64 + c4a) = b.u;
        }
    }
}

// ---------------- GEMM2: g[n][32] = dis[n] * (relu(in[n][128]) @ W[128][32]) ----------------

__global__ __launch_bounds__(256) void gemm2_k(const float* __restrict__ in,
                                               const float* __restrict__ W,
                                               const float* __restrict__ dis,
                                               float* __restrict__ out, int n_rows) {
    __shared__ float xs[64][132];
    __shared__ float wt[128][32];
    const int t = threadIdx.x;
    const int row0 = blockIdx.x * 64;

    #pragma unroll
    for (int i = 0; i < 8; ++i) {
        int q = t + i * 256;
        int row = q >> 5, c4 = (q & 31) * 4;
        float4 v = make_float4(0.f, 0.f, 0.f, 0.f);
        if (row0 + row < n_rows) {
            v = *(const float4*)(in + (size_t)(row0 + row) * 128 + c4);
            v.x = fmaxf(v.x, 0.f); v.y = fmaxf(v.y, 0.f);
            v.z = fmaxf(v.z, 0.f); v.w = fmaxf(v.w, 0.f);
        }
        *(float4*)&xs[row][c4] = v;
    }
    #pragma unroll
    for (int i = 0; i < 4; ++i) {
        int q = t + i * 256;
        int kk = q >> 3, c4 = (q & 7) * 4;
        *(float4*)&wt[kk][c4] = *(const float4*)(W + (size_t)kk * 32 + c4);
    }
    __syncthreads();

    const int c4 = (t & 7) * 4;
    const int r2 = (t >> 3) * 2;

    float acc[2][4];
    #pragma unroll
    for (int i = 0; i < 2; ++i)
        #pragma unroll
        for (int j = 0; j < 4; ++j) acc[i][j] = 0.f;

    #pragma unroll 4
    for (int k = 0; k < 128; ++k) {
        float x0 = xs[r2][k], x1 = xs[r2 + 1][k];
        float4 w = *(float4*)&wt[k][c4];
        acc[0][0] += x0 * w.x; acc[0][1] += x0 * w.y; acc[0][2] += x0 * w.z; acc[0][3] += x0 * w.w;
        acc[1][0] += x1 * w.x; acc[1][1] += x1 * w.y; acc[1][2] += x1 * w.z; acc[1][3] += x1 * w.w;
    }

    #pragma unroll
    for (int i = 0; i < 2; ++i) {
        int row = row0 + r2 + i;
        if (row < n_rows) {
            float sc = dis[row];
            *(float4*)(out + (size_t)row * 32 + c4) =
                make_float4(sc * acc[i][0], sc * acc[i][1], sc * acc[i][2], sc * acc[i][3]);
        }
    }
}

// ---------------- GEMM3: g[n][32] = dis[n] * (relu(in[n][32]) @ W[32][32]) ----------------

__global__ __launch_bounds__(256) void gemm3_k(const float* __restrict__ in,
                                               const float* __restrict__ W,
                                               const float* __restrict__ dis,
                                               float* __restrict__ out, int n_rows) {
    __shared__ float xs[64][36];
    __shared__ float wt[32][32];
    const int t = threadIdx.x;
    const int row0 = blockIdx.x * 64;

    #pragma unroll
    for (int i = 0; i < 2; ++i) {
        int q = t + i * 256;
        int row = q >> 3, c4 = (q & 7) * 4;
        float4 v = make_float4(0.f, 0.f, 0.f, 0.f);
        if (row0 + row < n_rows) {
            v = *(const float4*)(in + (size_t)(row0 + row) * 32 + c4);
            v.x = fmaxf(v.x, 0.f); v.y = fmaxf(v.y, 0.f);
            v.z = fmaxf(v.z, 0.f); v.w = fmaxf(v.w, 0.f);
        }
        *(float4*)&xs[row][c4] = v;
    }
    {
        int kk = t >> 3, c4 = (t & 7) * 4;
        *(float4*)&wt[kk][c4] = *(const float4*)(W + (size_t)kk * 32 + c4);
    }
    __syncthreads();

    const int c4 = (t & 7) * 4;
    const int r2 = (t >> 3) * 2;

    float acc[2][4];
    #pragma unroll
    for (int i = 0; i < 2; ++i)
        #pragma unroll
        for (int j = 0; j < 4; ++j) acc[i][j] = 0.f;

    #pragma unroll
    for (int k = 0; k < 32; ++k) {
        float x0 = xs[r2][k], x1 = xs[r2 + 1][k];
        float4 w = *(float4*)&wt[k][c4];
        acc[0][0] += x0 * w.x; acc[0][1] += x0 * w.y; acc[0][2] += x0 * w.z; acc[0][3] += x0 * w.w;
        acc[1][0] += x1 * w.x; acc[1][1] += x1 * w.y; acc[1][2] += x1 * w.z; acc[1][3] += x1 * w.w;
    }

    #pragma unroll
    for (int i = 0; i < 2; ++i) {
        int row = row0 + r2 + i;
        if (row < n_rows) {
            float sc = dis[row];
            *(float4*)(out + (size_t)row * 32 + c4) =
                make_float4(sc * acc[i][0], sc * acc[i][1], sc * acc[i][2], sc * acc[i][3]);
        }
    }
}

// ---------------- pull1 (fp16 g, 128-wide): 16 lanes/node, 8 feat/lane ----------------
// out[d][:] = b + dis[d] * ( g[d][:] + sum_e g[src][:] )

__global__ void pull1_k(const __half* __restrict__ g, const int* __restrict__ rowoff,
                        const int* __restrict__ deg, const int* __restrict__ csr,
                        const float* __restrict__ dis, const float* __restrict__ b,
                        float* __restrict__ out, int n_nodes) {
    int gt = blockIdx.x * blockDim.x + threadIdx.x;
    int node = gt >> 4;
    int f0 = (gt & 15) * 8;
    if (node >= n_nodes) return;
    int beg = rowoff[node];
    int end = beg + deg[node];
    float dd = dis[node];

    float acc[8];
    {
        F4H8 v; v.f = *(const float4*)(g + (size_t)node * 128 + f0);
        #pragma unroll
        for (int k = 0; k < 4; ++k) {
            float2 p = __half22float2(v.h[k]);
            acc[2 * k] = p.x; acc[2 * k + 1] = p.y;
        }
    }

    int j = beg;
    for (; j + 2 <= end; j += 2) {
        int s0 = csr[j];
        int s1 = csr[j + 1];
        F4H8 v0; v0.f = *(const float4*)(g + (size_t)s0 * 128 + f0);
        F4H8 v1; v1.f = *(const float4*)(g + (size_t)s1 * 128 + f0);
        #pragma unroll
        for (int k = 0; k < 4; ++k) {
            float2 p0 = __half22float2(v0.h[k]);
            float2 p1 = __half22float2(v1.h[k]);
            acc[2 * k]     += p0.x + p1.x;
            acc[2 * k + 1] += p0.y + p1.y;
        }
    }
    if (j < end) {
        int s = csr[j];
        F4H8 v; v.f = *(const float4*)(g + (size_t)s * 128 + f0);
        #pragma unroll
        for (int k = 0; k < 4; ++k) {
            float2 p = __half22float2(v.h[k]);
            acc[2 * k] += p.x; acc[2 * k + 1] += p.y;
        }
    }

    float* o = out + (size_t)node * 128 + f0;
    float4 b0 = *(const float4*)(b + f0);
    float4 b1 = *(const float4*)(b + f0 + 4);
    *(float4*)o = make_float4(b0.x + dd * acc[0], b0.y + dd * acc[1],
                              b0.z + dd * acc[2], b0.w + dd * acc[3]);
    *(float4*)(o + 4) = make_float4(b1.x + dd * acc[4], b1.y + dd * acc[5],
                                    b1.z + dd * acc[6], b1.w + dd * acc[7]);
}

// ---------------- pull2 (fp32 g, 32-wide): 8 lanes/node, 4 feat/lane ----------------

__global__ void pull2_k(const float* __restrict__ g, const int* __restrict__ rowoff,
                        const int* __restrict__ deg, const int* __restrict__ csr,
                        const float* __restrict__ dis, const float* __restrict__ b,
                        float* __restrict__ out, int n_nodes) {
    int gt = blockIdx.x * blockDim.x + threadIdx.x;
    int node = gt >> 3;
    int f0 = (gt & 7) * 4;
    if (node >= n_nodes) return;
    int beg = rowoff[node];
    int end = beg + deg[node];
    float dd = dis[node];

    float4 acc = *(const float4*)(g + (size_t)node * 32 + f0);

    int j = beg;
    for (; j + 2 <= end; j += 2) {
        int s0 = csr[j];
        int s1 = csr[j + 1];
        float4 h0 = *(const float4*)(g + (size_t)s0 * 32 + f0);
        float4 h1 = *(const float4*)(g + (size_t)s1 * 32 + f0);
        acc.x += h0.x + h1.x;
        acc.y += h0.y + h1.y;
        acc.z += h0.z + h1.z;
        acc.w += h0.w + h1.w;
    }
    if (j < end) {
        int s = csr[j];
        float4 hs = *(const float4*)(g + (size_t)s * 32 + f0);
        acc.x += hs.x; acc.y += hs.y; acc.z += hs.z; acc.w += hs.w;
    }

    float4 bb = *(const float4*)(b + f0);
    *(float4*)(out + (size_t)node * 32 + f0) =
        make_float4(bb.x + dd * acc.x, bb.y + dd * acc.y,
                    bb.z + dd * acc.z, bb.w + dd * acc.w);
}

// ---------------- fused pull3 + head (sel nodes only): 8 lanes/sel-entry ----------------

__global__ void pull_head_k(const float* __restrict__ g, const int* __restrict__ rowoff,
                            const int* __restrict__ deg, const int* __restrict__ csr,
                            const float* __restrict__ dis, const float* __restrict__ b3,
                            const int* __restrict__ sel, const float* __restrict__ Wl,
                            const float* __restrict__ bl, float* __restrict__ out, int n_sel) {
    int gt = blockIdx.x * blockDim.x + threadIdx.x;
    int t = gt >> 3;
    int f0 = (gt & 7) * 4;
    if (t >= n_sel) return;
    int node = sel[t];
    int beg = rowoff[node];
    int end = beg + deg[node];
    float dd = dis[node];

    float4 acc = *(const float4*)(g + (size_t)node * 32 + f0);

    int j = beg;
    for (; j + 2 <= end; j += 2) {
        int s0 = csr[j];
        int s1 = csr[j + 1];
        float4 h0 = *(const float4*)(g + (size_t)s0 * 32 + f0);
        float4 h1 = *(const float4*)(g + (size_t)s1 * 32 + f0);
        acc.x += h0.x + h1.x;
        acc.y += h0.y + h1.y;
        acc.z += h0.z + h1.z;
        acc.w += h0.w + h1.w;
    }
    if (j < end) {
        int s = csr[j];
        float4 hs = *(const float4*)(g + (size_t)s * 32 + f0);
        acc.x += hs.x; acc.y += hs.y; acc.z += hs.z; acc.w += hs.w;
    }

    float4 bb = *(const float4*)(b3 + f0);
    float a0 = bb.x + dd * acc.x;
    float a1 = bb.y + dd * acc.y;
    float a2 = bb.z + dd * acc.z;
    float a3 = bb.w + dd * acc.w;

    float l0 = a0 * Wl[(f0 + 0) * 2] + a1 * Wl[(f0 + 1) * 2]
             + a2 * Wl[(f0 + 2) * 2] + a3 * Wl[(f0 + 3) * 2];
    float l1 = a0 * Wl[(f0 + 0) * 2 + 1] + a1 * Wl[(f0 + 1) * 2 + 1]
             + a2 * Wl[(f0 + 2) * 2 + 1] + a3 * Wl[(f0 + 3) * 2 + 1];
    #pragma unroll
    for (int m = 1; m < 8; m <<= 1) {
        l0 += __shfl_xor(l0, m);
        l1 += __shfl_xor(l1, m);
    }
    if ((gt & 7) == 0) {
        l0 += bl[0]; l1 += bl[1];
        float mx = fmaxf(l0, l1);
        float e0 = expf(l0 - mx), e1 = expf(l1 - mx);
        float s = e0 + e1;
        float ls = logf(s);
        *(float2*)(out + (size_t)t * 2) = make_float2((l0 - mx) - ls, (l1 - mx) - ls);
        *(float2*)(out + 2 * (size_t)n_sel + (size_t)t * 2) = make_float2(e0 / s, e1 / s);
    }
}

// ---------------- launch ----------------

extern "C" void kernel_launch(void* const* d_in, const int* in_sizes, int n_in,
                              void* d_out, int out_size, void* d_ws, size_t ws_size,
                              hipStream_t stream) {
    const float* x  = (const float*)d_in[0];
    const int* edge = (const int*)d_in[1];
    const int* sel  = (const int*)d_in[2];
    const float* W1 = (const float*)d_in[4];
    const float* b1 = (const float*)d_in[5];
    const float* W2 = (const float*)d_in[6];
    const float* b2 = (const float*)d_in[7];
    const float* W3 = (const float*)d_in[8];
    const float* b3 = (const float*)d_in[9];
    const float* Wl = (const float*)d_in[10];
    const float* bl = (const float*)d_in[11];
    float* out = (float*)d_out;

    const int n_nodes = in_sizes[0] / F_IN;
    const int n_edges = in_sizes[1] / 2;
    const int n_sel   = in_sizes[2];
    const int* srcv = edge;
    const int* dstv = edge + n_edges;
    const int n_buckets = (n_nodes + NPB - 1) / NPB;   // 196
    const int n_gh = n_buckets * NBK;                  // 50176 <= 65536

    char* ws = (char*)d_ws;
    int*      deg      = (int*)ws;      ws += alignup((size_t)n_nodes * 4);
    float*    dis      = (float*)ws;    ws += alignup((size_t)n_nodes * 4);
    int*      rowoff   = (int*)ws;      ws += alignup((size_t)n_nodes * 4);
    int*      ghist    = (int*)ws;      ws += alignup((size_t)n_gh * 4);
    int*      goff     = (int*)ws;      ws += alignup((size_t)n_gh * 4);
    int*      partial2 = (int*)ws;      ws += alignup(1024);
    unsigned* tmp      = (unsigned*)ws; ws += alignup((size_t)n_edges * 4);
    int*      csr      = (int*)ws;      ws += alignup((size_t)n_edges * 4);
    char*     bufA     = ws;            ws += alignup((size_t)n_nodes * HID * 4);
    float*    bufB     = (float*)ws;

    const int B = 256;
    #define GRD(n) (((n) + B - 1) / B)
    const int nblk2 = GRD(n_gh);   // 196

    // CSR build: hist -> scan -> partition -> per-bucket finalize (no global per-node atomics)
    hist_k<<<NBK, 1024, 0, stream>>>(dstv, ghist, n_edges, n_buckets);
    scan_block_k<<<nblk2, B, 0, stream>>>(ghist, goff, partial2, n_gh);
    scan_partials_k<<<1, B, 0, stream>>>(partial2, nblk2);
    add2_k<<<nblk2, B, 0, stream>>>(goff, partial2, n_gh);
    scatter2_k<<<NBK, 1024, 0, stream>>>(srcv, dstv, goff, tmp, n_edges, n_buckets);
    binC_k<<<n_buckets, NPB, 0, stream>>>(tmp, goff, deg, dis, rowoff, csr, n_nodes, n_edges, n_buckets);

    const int gemm_blocks = (n_nodes + 63) / 64;

    // layer 1: g1 (fp16) = dis * (x @ W1); agg1 = b1 + dis*(g1 + gather)
    gemm1_k<<<gemm_blocks, B, 0, stream>>>(x, W1, dis, (__half*)bufA, n_nodes);
    pull1_k<<<GRD(n_nodes * 16), B, 0, stream>>>((const __half*)bufA, rowoff, deg, csr, dis, b1, bufB, n_nodes);

    // layer 2
    gemm2_k<<<gemm_blocks, B, 0, stream>>>(bufB, W2, dis, (float*)bufA, n_nodes);
    pull2_k<<<GRD(n_nodes * 8), B, 0, stream>>>((const float*)bufA, rowoff, deg, csr, dis, b2, bufB, n_nodes);

    // layer 3: g3 for all nodes; pull+head only for sel nodes
    gemm3_k<<<gemm_blocks, B, 0, stream>>>(bufB, W3, dis, (float*)bufA, n_nodes);
    pull_head_k<<<GRD(n_sel * 8), B, 0, stream>>>((const float*)bufA, rowoff, deg, csr, dis, b3,
                                                  sel, Wl, bl, out, n_sel);

    #undef GRD
}

// Round 8
// 139.256 us; speedup vs baseline: 2.6515x; 1.1034x over previous
//
#include <hip/hip_runtime.h>
#include <hip/hip_fp16.h>

#define F_IN 128
#define HID 128
#define HID4 32
#define NPB 256          // nodes per CSR bucket
#define SRC_BITS 17      // n_nodes = 50000 < 2^17 ; (d % NPB) << 17 fits 32b
#define NBK 256          // partition chunks/blocks (n_buckets*NBK <= 65536 for 2-level scan)
#define MAXBUCKET 256    // LDS counter array size (n_buckets = 196)

static inline size_t alignup(size_t x) { return (x + 255) & ~(size_t)255; }

typedef _Float16 half8 __attribute__((ext_vector_type(8)));
typedef float f32x4 __attribute__((ext_vector_type(4)));

union F4H8 { float4 f; __half2 h[4]; };   // 8 halfs = 16 B
union U2H4 { uint2 u; _Float16 h[4]; };   // 4 halfs = 8 B

// ---------------- pass 1: per-(block,bucket) histogram, LDS only ----------------

__global__ __launch_bounds__(1024) void hist_k(const int* __restrict__ dst,
                                               int* __restrict__ ghist, int ne, int n_buckets) {
    __shared__ int h[MAXBUCKET];
    const int t = threadIdx.x;
    for (int b = t; b < n_buckets; b += 1024) h[b] = 0;
    __syncthreads();
    const int chunk = (ne + NBK - 1) / NBK;
    const int beg = blockIdx.x * chunk;
    const int end = min(ne, beg + chunk);
    for (int e = beg + t; e < end; e += 1024)
        atomicAdd(&h[dst[e] / NPB], 1);           // LDS atomic
    __syncthreads();
    for (int b = t; b < n_buckets; b += 1024)
        ghist[(size_t)b * NBK + blockIdx.x] = h[b];  // bucket-major for flat scan
}

// ---------------- generic 2-level exclusive scan ----------------

__global__ void scan_block_k(const int* __restrict__ in, int* __restrict__ out,
                             int* __restrict__ partials, int n) {
    __shared__ int tmp[256];
    int i = blockIdx.x * 256 + threadIdx.x;
    int v = (i < n) ? in[i] : 0;
    tmp[threadIdx.x] = v;
    __syncthreads();
    for (int off = 1; off < 256; off <<= 1) {
        int t = (threadIdx.x >= off) ? tmp[threadIdx.x - off] : 0;
        __syncthreads();
        tmp[threadIdx.x] += t;
        __syncthreads();
    }
    if (i < n) out[i] = tmp[threadIdx.x] - v;
    if (threadIdx.x == 255) partials[blockIdx.x] = tmp[255];
}

__global__ void scan_partials_k(int* __restrict__ partials, int nb) {
    __shared__ int tmp[256];
    int v = (threadIdx.x < nb) ? partials[threadIdx.x] : 0;
    tmp[threadIdx.x] = v;
    __syncthreads();
    for (int off = 1; off < 256; off <<= 1) {
        int t = (threadIdx.x >= off) ? tmp[threadIdx.x - off] : 0;
        __syncthreads();
        tmp[threadIdx.x] += t;
        __syncthreads();
    }
    if (threadIdx.x < nb) partials[threadIdx.x] = tmp[threadIdx.x] - v;
}

__global__ void add2_k(int* __restrict__ goff, const int* __restrict__ partials, int n) {
    int i = blockIdx.x * 256 + threadIdx.x;
    if (i < n) goff[i] += partials[i >> 8];
}

// ---------------- pass 2: partition edges into bucket-ordered tmp (LDS cursors) ----------------

__global__ __launch_bounds__(1024) void scatter2_k(const int* __restrict__ src, const int* __restrict__ dst,
                                                   const int* __restrict__ goff,
                                                   unsigned* __restrict__ tmp, int ne, int n_buckets) {
    __shared__ int cur[MAXBUCKET];
    const int t = threadIdx.x;
    for (int b = t; b < n_buckets; b += 1024)
        cur[b] = goff[(size_t)b * NBK + blockIdx.x];
    __syncthreads();
    const int chunk = (ne + NBK - 1) / NBK;
    const int beg = blockIdx.x * chunk;
    const int end = min(ne, beg + chunk);
    for (int e = beg + t; e < end; e += 1024) {
        int d = dst[e];
        int s = src[e];
        int pos = atomicAdd(&cur[d / NPB], 1);    // LDS atomic
        tmp[pos] = ((unsigned)(d & (NPB - 1)) << SRC_BITS) | (unsigned)s;
    }
}

// ---------------- pass 3: per-bucket deg/dis/rowoff + final CSR placement ----------------

__global__ __launch_bounds__(NPB) void binC_k(const unsigned* __restrict__ tmp,
                                              const int* __restrict__ goff,
                                              int* __restrict__ deg, float* __restrict__ dis,
                                              int* __restrict__ rowoff, int* __restrict__ csr,
                                              int n_nodes, int ne, int n_buckets) {
    __shared__ int cnt[NPB];
    __shared__ int sc[NPB];
    const int t = threadIdx.x;
    const int bid = blockIdx.x;
    const int base = goff[(size_t)bid * NBK];
    const int end = (bid + 1 < n_buckets) ? goff[(size_t)(bid + 1) * NBK] : ne;

    cnt[t] = 0;
    __syncthreads();
    for (int j = base + t; j < end; j += NPB)
        atomicAdd(&cnt[tmp[j] >> SRC_BITS], 1);   // LDS atomic, per-node degree
    __syncthreads();

    int mydeg = cnt[t];
    sc[t] = mydeg;
    __syncthreads();
    for (int off = 1; off < NPB; off <<= 1) {     // Hillis-Steele inclusive scan
        int v = (t >= off) ? sc[t - off] : 0;
        __syncthreads();
        sc[t] += v;
        __syncthreads();
    }
    int excl = sc[t] - mydeg;
    int node = bid * NPB + t;
    if (node < n_nodes) {
        deg[node] = mydeg;
        dis[node] = rsqrtf((float)(mydeg + 1));
        rowoff[node] = base + excl;
    }
    cnt[t] = base + excl;                         // becomes placement cursor
    __syncthreads();
    for (int j = base + t; j < end; j += NPB) {
        unsigned e = tmp[j];
        int ld = e >> SRC_BITS;
        int s  = e & ((1u << SRC_BITS) - 1);
        int pos = atomicAdd(&cnt[ld], 1);
        csr[pos] = s;
    }
}

// ---------------- W1 pre-transpose to fp16: Wt[n][k] = (half)W[k][n] ----------------

__global__ void wprep_k(const float* __restrict__ W, _Float16* __restrict__ Wt) {
    int t = blockIdx.x * blockDim.x + threadIdx.x;
    if (t < 128 * 128) {
        int k = t >> 7, n = t & 127;
        Wt[n * 128 + k] = (_Float16)W[k * 128 + n];
    }
}

// ---------------- GEMM1 (MFMA fp16): g[n][128] = dis[n] * (x[n][128] @ W1) ----------------
// 64 rows/block, 256 threads = 4 waves; wave w owns rows w*16..w*16+15, all 128 cols.
// LDS rows padded to 136 halves (272 B = 16B-aligned, 2-way bank aliasing = free).

__global__ __launch_bounds__(256) void gemm1_mfma_k(const float* __restrict__ in,
                                                    const _Float16* __restrict__ Wt,
                                                    const float* __restrict__ dis,
                                                    __half* __restrict__ hout, int n_rows) {
    __shared__ _Float16 xs[64][136];
    __shared__ _Float16 wt[128][136];
    const int t = threadIdx.x;
    const int row0 = blockIdx.x * 64;

    // stage x (fp32 -> fp16): 64 rows x 32 quads = 2048 quads / 256 thr = 8 iters
    #pragma unroll
    for (int i = 0; i < 8; ++i) {
        int q = t + i * 256;
        int row = q >> 5, c4 = (q & 31) * 4;
        float4 v = make_float4(0.f, 0.f, 0.f, 0.f);
        if (row0 + row < n_rows) v = *(const float4*)(in + (size_t)(row0 + row) * 128 + c4);
        U2H4 cv;
        cv.h[0] = (_Float16)v.x; cv.h[1] = (_Float16)v.y;
        cv.h[2] = (_Float16)v.z; cv.h[3] = (_Float16)v.w;
        *(uint2*)&xs[row][c4] = cv.u;
    }
    // stage Wt (fp16, 16B chunks): 128 rows x 16 chunks = 2048 / 256 = 8 iters
    #pragma unroll
    for (int i = 0; i < 8; ++i) {
        int q = t + i * 256;
        int n = q >> 4, k0 = (q & 15) * 8;
        *(uint4*)&wt[n][k0] = *(const uint4*)(Wt + (size_t)n * 128 + k0);
    }
    __syncthreads();

    const int lane = t & 63;
    const int wave = t >> 6;
    const int r0 = wave * 16;
    const int lrow = lane & 15;
    const int kgrp = (lane >> 4) * 8;

    f32x4 acc[8];
    #pragma unroll
    for (int c = 0; c < 8; ++c) acc[c] = (f32x4){0.f, 0.f, 0.f, 0.f};

    #pragma unroll
    for (int kk = 0; kk < 4; ++kk) {
        const int k0 = kk * 32 + kgrp;
        half8 a = *(const half8*)&xs[r0 + lrow][k0];
        #pragma unroll
        for (int ct = 0; ct < 8; ++ct) {
            half8 b = *(const half8*)&wt[ct * 16 + lrow][k0];
            acc[ct] = __builtin_amdgcn_mfma_f32_16x16x32_f16(a, b, acc[ct], 0, 0, 0);
        }
    }

    // epilogue: C row = 4*(lane>>4)+i, col = ct*16 + (lane&15)
    const int rbase = row0 + r0 + (lane >> 4) * 4;
    #pragma unroll
    for (int i = 0; i < 4; ++i) {
        int row = rbase + i;
        if (row < n_rows) {
            float sc = dis[row];
            __half* p = hout + (size_t)row * 128 + lrow;
            #pragma unroll
            for (int ct = 0; ct < 8; ++ct)
                p[ct * 16] = __float2half(sc * acc[ct][i]);
        }
    }
}

// ---------------- GEMM2: g[n][32] = dis[n] * (relu(in[n][128]) @ W[128][32]) ----------------

__global__ __launch_bounds__(256) void gemm2_k(const float* __restrict__ in,
                                               const float* __restrict__ W,
                                               const float* __restrict__ dis,
                                               float* __restrict__ out, int n_rows) {
    __shared__ float xs[64][132];
    __shared__ float wt[128][32];
    const int t = threadIdx.x;
    const int row0 = blockIdx.x * 64;

    #pragma unroll
    for (int i = 0; i < 8; ++i) {
        int q = t + i * 256;
        int row = q >> 5, c4 = (q & 31) * 4;
        float4 v = make_float4(0.f, 0.f, 0.f, 0.f);
        if (row0 + row < n_rows) {
            v = *(const float4*)(in + (size_t)(row0 + row) * 128 + c4);
            v.x = fmaxf(v.x, 0.f); v.y = fmaxf(v.y, 0.f);
            v.z = fmaxf(v.z, 0.f); v.w = fmaxf(v.w, 0.f);
        }
        *(float4*)&xs[row][c4] = v;
    }
    #pragma unroll
    for (int i = 0; i < 4; ++i) {
        int q = t + i * 256;
        int kk = q >> 3, c4 = (q & 7) * 4;
        *(float4*)&wt[kk][c4] = *(const float4*)(W + (size_t)kk * 32 + c4);
    }
    __syncthreads();

    const int c4 = (t & 7) * 4;
    const int r2 = (t >> 3) * 2;

    float acc[2][4];
    #pragma unroll
    for (int i = 0; i < 2; ++i)
        #pragma unroll
        for (int j = 0; j < 4; ++j) acc[i][j] = 0.f;

    #pragma unroll 4
    for (int k = 0; k < 128; ++k) {
        float x0 = xs[r2][k], x1 = xs[r2 + 1][k];
        float4 w = *(float4*)&wt[k][c4];
        acc[0][0] += x0 * w.x; acc[0][1] += x0 * w.y; acc[0][2] += x0 * w.z; acc[0][3] += x0 * w.w;
        acc[1][0] += x1 * w.x; acc[1][1] += x1 * w.y; acc[1][2] += x1 * w.z; acc[1][3] += x1 * w.w;
    }

    #pragma unroll
    for (int i = 0; i < 2; ++i) {
        int row = row0 + r2 + i;
        if (row < n_rows) {
            float sc = dis[row];
            *(float4*)(out + (size_t)row * 32 + c4) =
                make_float4(sc * acc[i][0], sc * acc[i][1], sc * acc[i][2], sc * acc[i][3]);
        }
    }
}

// ---------------- GEMM3: g[n][32] = dis[n] * (relu(in[n][32]) @ W[32][32]) ----------------

__global__ __launch_bounds__(256) void gemm3_k(const float* __restrict__ in,
                                               const float* __restrict__ W,
                                               const float* __restrict__ dis,
                                               float* __restrict__ out, int n_rows) {
    __shared__ float xs[64][36];
    __shared__ float wt[32][32];
    const int t = threadIdx.x;
    const int row0 = blockIdx.x * 64;

    #pragma unroll
    for (int i = 0; i < 2; ++i) {
        int q = t + i * 256;
        int row = q >> 3, c4 = (q & 7) * 4;
        float4 v = make_float4(0.f, 0.f, 0.f, 0.f);
        if (row0 + row < n_rows) {
            v = *(const float4*)(in + (size_t)(row0 + row) * 32 + c4);
            v.x = fmaxf(v.x, 0.f); v.y = fmaxf(v.y, 0.f);
            v.z = fmaxf(v.z, 0.f); v.w = fmaxf(v.w, 0.f);
        }
        *(float4*)&xs[row][c4] = v;
    }
    {
        int kk = t >> 3, c4 = (t & 7) * 4;
        *(float4*)&wt[kk][c4] = *(const float4*)(W + (size_t)kk * 32 + c4);
    }
    __syncthreads();

    const int c4 = (t & 7) * 4;
    const int r2 = (t >> 3) * 2;

    float acc[2][4];
    #pragma unroll
    for (int i = 0; i < 2; ++i)
        #pragma unroll
        for (int j = 0; j < 4; ++j) acc[i][j] = 0.f;

    #pragma unroll
    for (int k = 0; k < 32; ++k) {
        float x0 = xs[r2][k], x1 = xs[r2 + 1][k];
        float4 w = *(float4*)&wt[k][c4];
        acc[0][0] += x0 * w.x; acc[0][1] += x0 * w.y; acc[0][2] += x0 * w.z; acc[0][3] += x0 * w.w;
        acc[1][0] += x1 * w.x; acc[1][1] += x1 * w.y; acc[1][2] += x1 * w.z; acc[1][3] += x1 * w.w;
    }

    #pragma unroll
    for (int i = 0; i < 2; ++i) {
        int row = row0 + r2 + i;
        if (row < n_rows) {
            float sc = dis[row];
            *(float4*)(out + (size_t)row * 32 + c4) =
                make_float4(sc * acc[i][0], sc * acc[i][1], sc * acc[i][2], sc * acc[i][3]);
        }
    }
}

// ---------------- pull1 (fp16 g, 128-wide): 16 lanes/node, 8 feat/lane ----------------
// out[d][:] = b + dis[d] * ( g[d][:] + sum_e g[src][:] )

__global__ void pull1_k(const __half* __restrict__ g, const int* __restrict__ rowoff,
                        const int* __restrict__ deg, const int* __restrict__ csr,
                        const float* __restrict__ dis, const float* __restrict__ b,
                        float* __restrict__ out, int n_nodes) {
    int gt = blockIdx.x * blockDim.x + threadIdx.x;
    int node = gt >> 4;
    int f0 = (gt & 15) * 8;
    if (node >= n_nodes) return;
    int beg = rowoff[node];
    int end = beg + deg[node];
    float dd = dis[node];

    float acc[8];
    {
        F4H8 v; v.f = *(const float4*)(g + (size_t)node * 128 + f0);
        #pragma unroll
        for (int k = 0; k < 4; ++k) {
            float2 p = __half22float2(v.h[k]);
            acc[2 * k] = p.x; acc[2 * k + 1] = p.y;
        }
    }

    int j = beg;
    for (; j + 2 <= end; j += 2) {
        int s0 = csr[j];
        int s1 = csr[j + 1];
        F4H8 v0; v0.f = *(const float4*)(g + (size_t)s0 * 128 + f0);
        F4H8 v1; v1.f = *(const float4*)(g + (size_t)s1 * 128 + f0);
        #pragma unroll
        for (int k = 0; k < 4; ++k) {
            float2 p0 = __half22float2(v0.h[k]);
            float2 p1 = __half22float2(v1.h[k]);
            acc[2 * k]     += p0.x + p1.x;
            acc[2 * k + 1] += p0.y + p1.y;
        }
    }
    if (j < end) {
        int s = csr[j];
        F4H8 v; v.f = *(const float4*)(g + (size_t)s * 128 + f0);
        #pragma unroll
        for (int k = 0; k < 4; ++k) {
            float2 p = __half22float2(v.h[k]);
            acc[2 * k] += p.x; acc[2 * k + 1] += p.y;
        }
    }

    float* o = out + (size_t)node * 128 + f0;
    float4 b0 = *(const float4*)(b + f0);
    float4 b1 = *(const float4*)(b + f0 + 4);
    *(float4*)o = make_float4(b0.x + dd * acc[0], b0.y + dd * acc[1],
                              b0.z + dd * acc[2], b0.w + dd * acc[3]);
    *(float4*)(o + 4) = make_float4(b1.x + dd * acc[4], b1.y + dd * acc[5],
                                    b1.z + dd * acc[6], b1.w + dd * acc[7]);
}

// ---------------- pull2 (fp32 g, 32-wide): 8 lanes/node, 4 feat/lane ----------------

__global__ void pull2_k(const float* __restrict__ g, const int* __restrict__ rowoff,
                        const int* __restrict__ deg, const int* __restrict__ csr,
                        const float* __restrict__ dis, const float* __restrict__ b,
                        float* __restrict__ out, int n_nodes) {
    int gt = blockIdx.x * blockDim.x + threadIdx.x;
    int node = gt >> 3;
    int f0 = (gt & 7) * 4;
    if (node >= n_nodes) return;
    int beg = rowoff[node];
    int end = beg + deg[node];
    float dd = dis[node];

    float4 acc = *(const float4*)(g + (size_t)node * 32 + f0);

    int j = beg;
    for (; j + 2 <= end; j += 2) {
        int s0 = csr[j];
        int s1 = csr[j + 1];
        float4 h0 = *(const float4*)(g + (size_t)s0 * 32 + f0);
        float4 h1 = *(const float4*)(g + (size_t)s1 * 32 + f0);
        acc.x += h0.x + h1.x;
        acc.y += h0.y + h1.y;
        acc.z += h0.z + h1.z;
        acc.w += h0.w + h1.w;
    }
    if (j < end) {
        int s = csr[j];
        float4 hs = *(const float4*)(g + (size_t)s * 32 + f0);
        acc.x += hs.x; acc.y += hs.y; acc.z += hs.z; acc.w += hs.w;
    }

    float4 bb = *(const float4*)(b + f0);
    *(float4*)(out + (size_t)node * 32 + f0) =
        make_float4(bb.x + dd * acc.x, bb.y + dd * acc.y,
                    bb.z + dd * acc.z, bb.w + dd * acc.w);
}

// ---------------- fused pull3 + head (sel nodes only): 8 lanes/sel-entry ----------------

__global__ void pull_head_k(const float* __restrict__ g, const int* __restrict__ rowoff,
                            const int* __restrict__ deg, const int* __restrict__ csr,
                            const float* __restrict__ dis, const float* __restrict__ b3,
                            const int* __restrict__ sel, const float* __restrict__ Wl,
                            const float* __restrict__ bl, float* __restrict__ out, int n_sel) {
    int gt = blockIdx.x * blockDim.x + threadIdx.x;
    int t = gt >> 3;
    int f0 = (gt & 7) * 4;
    if (t >= n_sel) return;
    int node = sel[t];
    int beg = rowoff[node];
    int end = beg + deg[node];
    float dd = dis[node];

    float4 acc = *(const float4*)(g + (size_t)node * 32 + f0);

    int j = beg;
    for (; j + 2 <= end; j += 2) {
        int s0 = csr[j];
        int s1 = csr[j + 1];
        float4 h0 = *(const float4*)(g + (size_t)s0 * 32 + f0);
        float4 h1 = *(const float4*)(g + (size_t)s1 * 32 + f0);
        acc.x += h0.x + h1.x;
        acc.y += h0.y + h1.y;
        acc.z += h0.z + h1.z;
        acc.w += h0.w + h1.w;
    }
    if (j < end) {
        int s = csr[j];
        float4 hs = *(const float4*)(g + (size_t)s * 32 + f0);
        acc.x += hs.x; acc.y += hs.y; acc.z += hs.z; acc.w += hs.w;
    }

    float4 bb = *(const float4*)(b3 + f0);
    float a0 = bb.x + dd * acc.x;
    float a1 = bb.y + dd * acc.y;
    float a2 = bb.z + dd * acc.z;
    float a3 = bb.w + dd * acc.w;

    float l0 = a0 * Wl[(f0 + 0) * 2] + a1 * Wl[(f0 + 1) * 2]
             + a2 * Wl[(f0 + 2) * 2] + a3 * Wl[(f0 + 3) * 2];
    float l1 = a0 * Wl[(f0 + 0) * 2 + 1] + a1 * Wl[(f0 + 1) * 2 + 1]
             + a2 * Wl[(f0 + 2) * 2 + 1] + a3 * Wl[(f0 + 3) * 2 + 1];
    #pragma unroll
    for (int m = 1; m < 8; m <<= 1) {
        l0 += __shfl_xor(l0, m);
        l1 += __shfl_xor(l1, m);
    }
    if ((gt & 7) == 0) {
        l0 += bl[0]; l1 += bl[1];
        float mx = fmaxf(l0, l1);
        float e0 = expf(l0 - mx), e1 = expf(l1 - mx);
        float s = e0 + e1;
        float ls = logf(s);
        *(float2*)(out + (size_t)t * 2) = make_float2((l0 - mx) - ls, (l1 - mx) - ls);
        *(float2*)(out + 2 * (size_t)n_sel + (size_t)t * 2) = make_float2(e0 / s, e1 / s);
    }
}

// ---------------- launch ----------------

extern "C" void kernel_launch(void* const* d_in, const int* in_sizes, int n_in,
                              void* d_out, int out_size, void* d_ws, size_t ws_size,
                              hipStream_t stream) {
    const float* x  = (const float*)d_in[0];
    const int* edge = (const int*)d_in[1];
    const int* sel  = (const int*)d_in[2];
    const float* W1 = (const float*)d_in[4];
    const float* b1 = (const float*)d_in[5];
    const float* W2 = (const float*)d_in[6];
    const float* b2 = (const float*)d_in[7];
    const float* W3 = (const float*)d_in[8];
    const float* b3 = (const float*)d_in[9];
    const float* Wl = (const float*)d_in[10];
    const float* bl = (const float*)d_in[11];
    float* out = (float*)d_out;

    const int n_nodes = in_sizes[0] / F_IN;
    const int n_edges = in_sizes[1] / 2;
    const int n_sel   = in_sizes[2];
    const int* srcv = edge;
    const int* dstv = edge + n_edges;
    const int n_buckets = (n_nodes + NPB - 1) / NPB;   // 196
    const int n_gh = n_buckets * NBK;                  // 50176 <= 65536

    char* ws = (char*)d_ws;
    int*       deg      = (int*)ws;       ws += alignup((size_t)n_nodes * 4);
    float*     dis      = (float*)ws;     ws += alignup((size_t)n_nodes * 4);
    int*       rowoff   = (int*)ws;       ws += alignup((size_t)n_nodes * 4);
    int*       ghist    = (int*)ws;       ws += alignup((size_t)n_gh * 4);
    int*       goff     = (int*)ws;       ws += alignup((size_t)n_gh * 4);
    int*       partial2 = (int*)ws;       ws += alignup(1024);
    _Float16*  Wt       = (_Float16*)ws;  ws += alignup(128 * 128 * 2);
    unsigned*  tmp      = (unsigned*)ws;  ws += alignup((size_t)n_edges * 4);
    int*       csr      = (int*)ws;       ws += alignup((size_t)n_edges * 4);
    char*      bufA     = ws;             ws += alignup((size_t)n_nodes * HID * 4);
    float*     bufB     = (float*)ws;

    const int B = 256;
    #define GRD(n) (((n) + B - 1) / B)
    const int nblk2 = GRD(n_gh);   // 196

    // CSR build: hist -> scan -> partition -> per-bucket finalize (no global per-node atomics)
    hist_k<<<NBK, 1024, 0, stream>>>(dstv, ghist, n_edges, n_buckets);
    scan_block_k<<<nblk2, B, 0, stream>>>(ghist, goff, partial2, n_gh);
    scan_partials_k<<<1, B, 0, stream>>>(partial2, nblk2);
    add2_k<<<nblk2, B, 0, stream>>>(goff, partial2, n_gh);
    scatter2_k<<<NBK, 1024, 0, stream>>>(srcv, dstv, goff, tmp, n_edges, n_buckets);
    binC_k<<<n_buckets, NPB, 0, stream>>>(tmp, goff, deg, dis, rowoff, csr, n_nodes, n_edges, n_buckets);

    const int gemm_blocks = (n_nodes + 63) / 64;

    // layer 1: g1 (fp16) = dis * (x @ W1) via MFMA; agg1 = b1 + dis*(g1 + gather)
    wprep_k<<<GRD(128 * 128), B, 0, stream>>>(W1, Wt);
    gemm1_mfma_k<<<gemm_blocks, B, 0, stream>>>(x, Wt, dis, (__half*)bufA, n_nodes);
    pull1_k<<<GRD(n_nodes * 16), B, 0, stream>>>((const __half*)bufA, rowoff, deg, csr, dis, b1, bufB, n_nodes);

    // layer 2
    gemm2_k<<<gemm_blocks, B, 0, stream>>>(bufB, W2, dis, (float*)bufA, n_nodes);
    pull2_k<<<GRD(n_nodes * 8), B, 0, stream>>>((const float*)bufA, rowoff, deg, csr, dis, b2, bufB, n_nodes);

    // layer 3: g3 for all nodes; pull+head only for sel nodes
    gemm3_k<<<gemm_blocks, B, 0, stream>>>(bufB, W3, dis, (float*)bufA, n_nodes);
    pull_head_k<<<GRD(n_sel * 8), B, 0, stream>>>((const float*)bufA, rowoff, deg, csr, dis, b3,
                                                  sel, Wl, bl, out, n_sel);

    #undef GRD
}